// Round 1
// baseline (9933.846 us; speedup 1.0000x reference)
//
#include <hip/hip_runtime.h>
#include <cstdint>
#include <cstddef>

// LSTM: B=64, T=512, D=128, H=512, O=256.
// Strategy:
//  - Persistent cooperative-style kernel: 256 wgs (<=256 CUs, co-resident by
//    construction), 8 batch-groups x 32 col-groups. Each wg owns 8 batches and
//    16 h-columns (64 gate columns). U/W column slices stream from L2/L1 each
//    step; x@W is computed on the fly (no xz materialization).
//  - Per batch-group barrier (32 wgs) per timestep via monotonic device-scope
//    atomic counter + __threadfence (release/acquire), h double-buffered in ws.
//  - All math f32 (zero precision risk this round).
//  - Second kernel: hs @ Wo + bo tiled f32 GEMM.
// Workspace: hs f32 64MB + hbuf 256KB + counters (needs ~64.6MB of d_ws).

namespace {
constexpr int B  = 64;
constexpr int T  = 512;
constexpr int D  = 128;
constexpr int H  = 512;
constexpr int G4 = 4 * H;          // 2048
constexpr int GB = 8;              // batch groups
constexpr int GC = 32;             // col groups
constexpr int NB = B / GB;         // 8 batches per wg
constexpr int NC = H / GC;         // 16 h-cols per wg
constexpr int NCC = 4 * NC;        // 64 gate cols per wg
constexpr int THREADS = 256;
constexpr int KS = 16;             // k-splits over K=512 (32 k each, interleaved)
constexpr int ZSTRIDE = NB * NCC + 4;  // 516, breaks power-of-2 LDS stride
}

__device__ __forceinline__ float sigf(float z) { return 1.0f / (1.0f + __expf(-z)); }

__global__ void zero_ctr(unsigned* __restrict__ c) {
  c[threadIdx.x] = 0u;   // 256 uints (8 groups, stride 32 = 128B apart)
}

__global__ __launch_bounds__(THREADS) void lstm_seq(
    const float* __restrict__ x, const float* __restrict__ h0,
    const float* __restrict__ c0, const float* __restrict__ W,
    const float* __restrict__ U, const float* __restrict__ bias,
    float* __restrict__ hs,      // ws [B][T][H]
    float* __restrict__ hbuf,    // ws [2][B][H]
    unsigned* __restrict__ ctr)  // ws [8 groups * 32]
{
  const int tid = threadIdx.x;
  const int g   = blockIdx.x & (GB - 1);  // batch group (blockIdx%8 -> same XCD heuristic)
  const int cg  = blockIdx.x / GB;        // col group
  const int b0  = g * NB;
  const int hc0 = cg * NC;

  __shared__ float h_lds[NB][H];          // 16 KB
  __shared__ float x_lds[NB][D];          // 4 KB
  __shared__ float zpart[KS * ZSTRIDE];   // ~33 KB
  __shared__ float zfull[NB][NCC];        // 2 KB
  __shared__ float c_lds[NB][NC];         // 0.5 KB

  // init cell state (wg-private, persistent in LDS)
  if (tid < NB * NC) {
    int b = tid / NC, hc = tid % NC;
    c_lds[b][hc] = c0[(size_t)(b0 + b) * H + hc0 + hc];
  }

  // dot-product work mapping: thread = (col-quad cq, k-split ks)
  const int cq  = tid & 15;         // 4 gate cols: cc0..cc0+3
  const int ks  = tid >> 4;         // 16 k-splits; k = 64*j + 4*ks + kk (interleaved)
  const int cc0 = cq * 4;
  const int gate  = cc0 >> 4;                    // 0..3 (i,f,g,o)
  const int gcol0 = gate * H + hc0 + (cc0 & 15); // global gate-col base (4 contiguous)

  unsigned* myctr = ctr + g * 32;

  for (int t = 0; t < T; ++t) {
    // ---- stage h (group's 8 batches) and x_t into LDS ----
    const float4* hsrc = (t == 0)
        ? (const float4*)(h0 + (size_t)b0 * H)
        : (const float4*)(hbuf + ((size_t)(((t - 1) & 1) * B + b0)) * H);
#pragma unroll
    for (int i = 0; i < (NB * H / 4) / THREADS; ++i)   // 4 float4 per thread
      ((float4*)&h_lds[0][0])[tid + i * THREADS] = hsrc[tid + i * THREADS];
    {
      int b = tid >> 5, dq = tid & 31;                 // 256 float4 total
      ((float4*)&x_lds[0][0])[tid] =
          *(const float4*)&x[(((size_t)(b0 + b)) * T + t) * D + dq * 4];
    }
    __syncthreads();

    // ---- z partials: acc[b][j] over this thread's k-slice ----
    float acc[NB][4];
#pragma unroll
    for (int b = 0; b < NB; ++b) { acc[b][0] = 0.f; acc[b][1] = 0.f; acc[b][2] = 0.f; acc[b][3] = 0.f; }

    // recurrent part: h @ U  (K=512)
    {
      const float* Up = U + (size_t)(4 * ks) * G4 + gcol0;
#pragma unroll
      for (int j = 0; j < 8; ++j) {
        const float* Uj = Up + (size_t)(64 * j) * G4;
        float4 u0 = *(const float4*)(Uj + 0 * (size_t)G4);
        float4 u1 = *(const float4*)(Uj + 1 * (size_t)G4);
        float4 u2 = *(const float4*)(Uj + 2 * (size_t)G4);
        float4 u3 = *(const float4*)(Uj + 3 * (size_t)G4);
        const int kb = 64 * j + 4 * ks;
#pragma unroll
        for (int b = 0; b < NB; ++b) {
          float4 h4 = *(const float4*)&h_lds[b][kb];
          acc[b][0] += h4.x * u0.x + h4.y * u1.x + h4.z * u2.x + h4.w * u3.x;
          acc[b][1] += h4.x * u0.y + h4.y * u1.y + h4.z * u2.y + h4.w * u3.y;
          acc[b][2] += h4.x * u0.z + h4.y * u1.z + h4.z * u2.z + h4.w * u3.z;
          acc[b][3] += h4.x * u0.w + h4.y * u1.w + h4.z * u2.w + h4.w * u3.w;
        }
      }
    }
    // input part: x_t @ W  (K=128), same interleave, j=0..1
    {
      const float* Wp = W + (size_t)(4 * ks) * G4 + gcol0;
#pragma unroll
      for (int j = 0; j < 2; ++j) {
        const float* Wj = Wp + (size_t)(64 * j) * G4;
        float4 w0 = *(const float4*)(Wj + 0 * (size_t)G4);
        float4 w1 = *(const float4*)(Wj + 1 * (size_t)G4);
        float4 w2 = *(const float4*)(Wj + 2 * (size_t)G4);
        float4 w3 = *(const float4*)(Wj + 3 * (size_t)G4);
        const int db = 64 * j + 4 * ks;
#pragma unroll
        for (int b = 0; b < NB; ++b) {
          float4 x4 = *(const float4*)&x_lds[b][db];
          acc[b][0] += x4.x * w0.x + x4.y * w1.x + x4.z * w2.x + x4.w * w3.x;
          acc[b][1] += x4.x * w0.y + x4.y * w1.y + x4.z * w2.y + x4.w * w3.y;
          acc[b][2] += x4.x * w0.z + x4.y * w1.z + x4.z * w2.z + x4.w * w3.z;
          acc[b][3] += x4.x * w0.w + x4.y * w1.w + x4.z * w2.w + x4.w * w3.w;
        }
      }
    }

    // ---- store partials, reduce across 16 k-splits, add bias ----
#pragma unroll
    for (int b = 0; b < NB; ++b)
      *(float4*)&zpart[ks * ZSTRIDE + b * NCC + cc0] =
          make_float4(acc[b][0], acc[b][1], acc[b][2], acc[b][3]);
    __syncthreads();

#pragma unroll
    for (int e = 0; e < 2; ++e) {
      int p  = tid * 2 + e;          // 512 (b,cc) pairs
      int b  = p >> 6, cc = p & 63;
      float s = bias[(cc >> 4) * H + hc0 + (cc & 15)];
#pragma unroll
      for (int k2 = 0; k2 < KS; ++k2) s += zpart[k2 * ZSTRIDE + b * NCC + cc];
      zfull[b][cc] = s;
    }
    __syncthreads();

    // ---- gate combine, state update, h_new publish ----
    if (tid < NB * NC) {
      int b = tid >> 4, hc = tid & 15;
      float zi = zfull[b][hc];
      float zf = zfull[b][NC + hc];
      float zg = zfull[b][2 * NC + hc];
      float zo = zfull[b][3 * NC + hc];
      float ii = sigf(zi), ff = sigf(zf), gg = tanhf(zg), oo = sigf(zo);
      float c  = ff * c_lds[b][hc] + ii * gg;
      c_lds[b][hc] = c;
      float hn = oo * tanhf(c);
      hbuf[((size_t)((t & 1) * B + b0 + b)) * H + hc0 + hc] = hn;
      hs[(((size_t)(b0 + b)) * T + t) * H + hc0 + hc] = hn;
    }
    __syncthreads();   // drains vmcnt: all h stores complete (in L2)

    // ---- per-group device-scope barrier (monotonic counter) ----
    if (tid == 0) {
      __threadfence();  // release: writeback L2 -> device-coherent
      __hip_atomic_fetch_add(myctr, 1u, __ATOMIC_RELEASE, __HIP_MEMORY_SCOPE_AGENT);
      const unsigned target = (unsigned)(GC * (t + 1));
      while (__hip_atomic_load(myctr, __ATOMIC_ACQUIRE, __HIP_MEMORY_SCOPE_AGENT) < target)
        __builtin_amdgcn_s_sleep(2);
      __threadfence();  // acquire: invalidate stale L1/L2 lines
    }
    __syncthreads();
  }
}

// ---- output projection: out[M,256] = hs[M,512] @ Wo[512,256] + bo ----
__global__ __launch_bounds__(256) void out_gemm(
    const float* __restrict__ A, const float* __restrict__ Wo,
    const float* __restrict__ bo, float* __restrict__ out)
{
  __shared__ float As[64][33];   // +1 pad breaks bank conflicts
  __shared__ float Bs[32][64];
  const int m0 = blockIdx.x * 64;
  const int n0 = blockIdx.y * 64;
  const int tid = threadIdx.x;
  const int tx = tid & 15, ty = tid >> 4;

  float acc[4][4];
#pragma unroll
  for (int i = 0; i < 4; ++i)
#pragma unroll
    for (int j = 0; j < 4; ++j) acc[i][j] = 0.f;

  for (int k0 = 0; k0 < 512; k0 += 32) {
#pragma unroll
    for (int it = 0; it < 2; ++it) {         // A tile: 64r x 32k
      int r  = (tid >> 3) + it * 32;
      int kq = (tid & 7) * 4;
      float4 v = *(const float4*)&A[(size_t)(m0 + r) * 512 + k0 + kq];
      As[r][kq + 0] = v.x; As[r][kq + 1] = v.y; As[r][kq + 2] = v.z; As[r][kq + 3] = v.w;
    }
#pragma unroll
    for (int it = 0; it < 2; ++it) {         // B tile: 32k x 64n
      int kk = (tid >> 4) + it * 16;
      int nq = (tid & 15) * 4;
      *(float4*)&Bs[kk][nq] = *(const float4*)&Wo[(size_t)(k0 + kk) * 256 + n0 + nq];
    }
    __syncthreads();
#pragma unroll
    for (int kk = 0; kk < 32; ++kk) {
      float a[4], b[4];
#pragma unroll
      for (int i = 0; i < 4; ++i) a[i] = As[ty * 4 + i][kk];
#pragma unroll
      for (int j = 0; j < 4; ++j) b[j] = Bs[kk][tx * 4 + j];
#pragma unroll
      for (int i = 0; i < 4; ++i)
#pragma unroll
        for (int j = 0; j < 4; ++j) acc[i][j] += a[i] * b[j];
    }
    __syncthreads();
  }
#pragma unroll
  for (int i = 0; i < 4; ++i) {
    int m = m0 + ty * 4 + i;
#pragma unroll
    for (int j = 0; j < 4; ++j) {
      int n = n0 + tx * 4 + j;
      out[(size_t)m * 256 + n] = acc[i][j] + bo[n];
    }
  }
}

extern "C" void kernel_launch(void* const* d_in, const int* in_sizes, int n_in,
                              void* d_out, int out_size, void* d_ws, size_t ws_size,
                              hipStream_t stream) {
  const float* x  = (const float*)d_in[0];
  const float* h0 = (const float*)d_in[1];
  const float* c0 = (const float*)d_in[2];
  const float* W  = (const float*)d_in[3];
  const float* U  = (const float*)d_in[4];
  const float* bv = (const float*)d_in[5];
  const float* Wo = (const float*)d_in[6];
  const float* bo = (const float*)d_in[7];
  float* out = (float*)d_out;

  float*    hs   = (float*)d_ws;                       // 64 MB
  float*    hbuf = hs + (size_t)B * T * H;             // 256 KB
  unsigned* ctr  = (unsigned*)(hbuf + 2 * (size_t)B * H);

  hipLaunchKernelGGL(zero_ctr, dim3(1), dim3(256), 0, stream, ctr);
  hipLaunchKernelGGL(lstm_seq, dim3(GB * GC), dim3(THREADS), 0, stream,
                     x, h0, c0, W, U, bv, hs, hbuf, ctr);
  hipLaunchKernelGGL(out_gemm, dim3((B * T) / 64, 256 / 64), dim3(256), 0, stream,
                     hs, Wo, bo, out);
}

// Round 2
// 7022.155 us; speedup vs baseline: 1.4146x; 1.4146x over previous
//
#include <hip/hip_runtime.h>
#include <cstdint>
#include <cstddef>

// LSTM: B=64, T=512, D=128, H=512, O=256.
// Persistent 256-wg kernel: 8 batch-groups x 32 col-groups; each wg owns
// 8 batches x 16 h-cols (64 gate cols). U/W column slices stay L2-resident
// (no cache-invalidating fences!). h exchanged through cache-bypassing
// agent-scope relaxed atomics; per-group monotonic-counter barrier with
// RELAXED polls only. x@W computed before the spin to hide barrier latency.
// Workspace: hs f32 64MB + hbuf 256KB + counters.

namespace {
constexpr int B  = 64;
constexpr int T  = 512;
constexpr int D  = 128;
constexpr int H  = 512;
constexpr int G4 = 4 * H;          // 2048
constexpr int GB = 8;              // batch groups
constexpr int GC = 32;             // col groups (barrier participants per group)
constexpr int NB = B / GB;         // 8 batches per wg
constexpr int NC = H / GC;         // 16 h-cols per wg
constexpr int NCC = 4 * NC;        // 64 gate cols per wg
constexpr int THREADS = 256;
constexpr int KS = 16;             // k-splits (each covers 32 of K=512, 8 of D=128)
constexpr int ZSTRIDE = NB * NCC + 4;  // 516, breaks power-of-2 LDS stride
}

__device__ __forceinline__ float sigf(float z) {
  return __fdividef(1.0f, 1.0f + __expf(-z));
}
__device__ __forceinline__ float tanhf_fast(float z) {
  float e = __expf(2.0f * z);
  return 1.0f - __fdividef(2.0f, e + 1.0f);
}

__global__ void zero_ctr(unsigned* __restrict__ c) {
  c[threadIdx.x] = 0u;   // 8 groups at stride 32 u32 (128B apart)
}

__global__ __launch_bounds__(THREADS) void lstm_seq(
    const float* __restrict__ x, const float* __restrict__ h0,
    const float* __restrict__ c0, const float* __restrict__ W,
    const float* __restrict__ U, const float* __restrict__ bias,
    float* __restrict__ hs,      // ws [B][T][H]
    float* __restrict__ hbuf,    // ws [2][B][H]  (coherent h exchange)
    unsigned* __restrict__ ctr)  // ws [8 groups * 32]
{
  const int tid = threadIdx.x;
  const int g   = blockIdx.x & (GB - 1);
  const int cg  = blockIdx.x / GB;
  const int b0  = g * NB;
  const int hc0 = cg * NC;

  __shared__ float h_lds[NB][H];          // 16 KB
  __shared__ float zpart[KS * ZSTRIDE];   // ~33 KB
  __shared__ float zfull[NB][NCC];        // 2 KB
  __shared__ float c_lds[NB][NC];         // 0.5 KB

  if (tid < NB * NC) {
    int b = tid / NC, hc = tid % NC;
    c_lds[b][hc] = c0[(size_t)(b0 + b) * H + hc0 + hc];
  }

  const int cq  = tid & 15;          // 4 gate cols cc0..cc0+3
  const int ks  = tid >> 4;          // 16 k-splits; k = 64*j + 4*ks + kk
  const int cc0 = cq * 4;
  const int gate  = cc0 >> 4;
  const int gcol0 = gate * H + hc0 + (cc0 & 15);

  // hoisted bias for the reduce phase (thread handles p = 2*tid, 2*tid+1)
  float bias_r[2];
#pragma unroll
  for (int e = 0; e < 2; ++e) {
    int cc = (tid * 2 + e) & 63;
    bias_r[e] = bias[(cc >> 4) * H + hc0 + (cc & 15)];
  }

  unsigned* myctr = ctr + g * 32;

  for (int t = 0; t < T; ++t) {
    // ---- phase A (h-independent): acc init + x_t @ W partials ----
    float acc[NB][4];
#pragma unroll
    for (int b = 0; b < NB; ++b) {
      acc[b][0] = 0.f; acc[b][1] = 0.f; acc[b][2] = 0.f; acc[b][3] = 0.f;
    }
    {
      const float* Wp = W + (size_t)(4 * ks) * G4 + gcol0;
#pragma unroll
      for (int j = 0; j < 2; ++j) {
        const float* Wj = Wp + (size_t)(64 * j) * G4;
        float4 w0 = *(const float4*)(Wj + 0 * (size_t)G4);
        float4 w1 = *(const float4*)(Wj + 1 * (size_t)G4);
        float4 w2 = *(const float4*)(Wj + 2 * (size_t)G4);
        float4 w3 = *(const float4*)(Wj + 3 * (size_t)G4);
        const int db = 64 * j + 4 * ks;
#pragma unroll
        for (int b = 0; b < NB; ++b) {
          float4 x4 = *(const float4*)&x[(((size_t)(b0 + b)) * T + t) * D + db];
          acc[b][0] += x4.x * w0.x + x4.y * w1.x + x4.z * w2.x + x4.w * w3.x;
          acc[b][1] += x4.x * w0.y + x4.y * w1.y + x4.z * w2.y + x4.w * w3.y;
          acc[b][2] += x4.x * w0.z + x4.y * w1.z + x4.z * w2.z + x4.w * w3.z;
          acc[b][3] += x4.x * w0.w + x4.y * w1.w + x4.z * w2.w + x4.w * w3.w;
        }
      }
    }

    // ---- wait for h(t-1) from the group's 32 wgs (RELAXED polls only) ----
    if (t > 0 && tid == 0) {
      const unsigned target = (unsigned)(GC * t);
      while (__hip_atomic_load(myctr, __ATOMIC_RELAXED, __HIP_MEMORY_SCOPE_AGENT) < target)
        __builtin_amdgcn_s_sleep(2);
      asm volatile("" ::: "memory");  // compiler-only fence; no cache ops
    }
    __syncthreads();

    // ---- stage h(t-1) into LDS (cache-bypassing coherent loads) ----
    if (t == 0) {
      const float4* hsrc = (const float4*)(h0 + (size_t)b0 * H);
#pragma unroll
      for (int i = 0; i < (NB * H / 4) / THREADS; ++i)
        ((float4*)&h_lds[0][0])[tid + i * THREADS] = hsrc[tid + i * THREADS];
    } else {
      const float* src = hbuf + ((size_t)(((t - 1) & 1) * B + b0)) * H;
#pragma unroll
      for (int i = 0; i < NB * H / THREADS; ++i)
        ((float*)&h_lds[0][0])[tid + i * THREADS] =
            __hip_atomic_load(src + tid + i * THREADS,
                              __ATOMIC_RELAXED, __HIP_MEMORY_SCOPE_AGENT);
    }
    __syncthreads();

    // ---- h @ U partials (U stays L2-resident: no invalidates anywhere) ----
    {
      const float* Up = U + (size_t)(4 * ks) * G4 + gcol0;
#pragma unroll
      for (int j = 0; j < 8; ++j) {
        const float* Uj = Up + (size_t)(64 * j) * G4;
        float4 u0 = *(const float4*)(Uj + 0 * (size_t)G4);
        float4 u1 = *(const float4*)(Uj + 1 * (size_t)G4);
        float4 u2 = *(const float4*)(Uj + 2 * (size_t)G4);
        float4 u3 = *(const float4*)(Uj + 3 * (size_t)G4);
        const int kb = 64 * j + 4 * ks;
#pragma unroll
        for (int b = 0; b < NB; ++b) {
          float4 h4 = *(const float4*)&h_lds[b][kb];
          acc[b][0] += h4.x * u0.x + h4.y * u1.x + h4.z * u2.x + h4.w * u3.x;
          acc[b][1] += h4.x * u0.y + h4.y * u1.y + h4.z * u2.y + h4.w * u3.y;
          acc[b][2] += h4.x * u0.z + h4.y * u1.z + h4.z * u2.z + h4.w * u3.z;
          acc[b][3] += h4.x * u0.w + h4.y * u1.w + h4.z * u2.w + h4.w * u3.w;
        }
      }
    }

    // ---- store partials, reduce across 16 k-splits, add bias ----
#pragma unroll
    for (int b = 0; b < NB; ++b)
      *(float4*)&zpart[ks * ZSTRIDE + b * NCC + cc0] =
          make_float4(acc[b][0], acc[b][1], acc[b][2], acc[b][3]);
    __syncthreads();

#pragma unroll
    for (int e = 0; e < 2; ++e) {
      int p  = tid * 2 + e;          // 512 (b,cc) pairs
      int b  = p >> 6, cc = p & 63;
      float s = bias_r[e];
#pragma unroll
      for (int k2 = 0; k2 < KS; ++k2) s += zpart[k2 * ZSTRIDE + b * NCC + cc];
      zfull[b][cc] = s;
    }
    __syncthreads();

    // ---- gates, state update, publish h(t) ----
    if (tid < NB * NC) {
      int b = tid >> 4, hc = tid & 15;
      float zi = zfull[b][hc];
      float zf = zfull[b][NC + hc];
      float zg = zfull[b][2 * NC + hc];
      float zo = zfull[b][3 * NC + hc];
      float ii = sigf(zi), ff = sigf(zf), gg = tanhf_fast(zg), oo = sigf(zo);
      float c  = ff * c_lds[b][hc] + ii * gg;
      c_lds[b][hc] = c;
      float hn = oo * tanhf_fast(c);
      __hip_atomic_store(hbuf + ((size_t)((t & 1) * B + b0 + b)) * H + hc0 + hc,
                         hn, __ATOMIC_RELAXED, __HIP_MEMORY_SCOPE_AGENT);
      hs[(((size_t)(b0 + b)) * T + t) * H + hc0 + hc] = hn;
    }
    // ensure THIS wave's h stores reached the coherence point, then barrier
    asm volatile("s_waitcnt vmcnt(0)" ::: "memory");
    __syncthreads();

    // ---- signal h(t) ready (monotonic counter, no fences) ----
    if (tid == 0)
      __hip_atomic_fetch_add(myctr, 1u, __ATOMIC_RELAXED, __HIP_MEMORY_SCOPE_AGENT);
  }
}

// ---- output projection: out[M,256] = hs[M,512] @ Wo[512,256] + bo ----
__global__ __launch_bounds__(256) void out_gemm(
    const float* __restrict__ A, const float* __restrict__ Wo,
    const float* __restrict__ bo, float* __restrict__ out)
{
  __shared__ float As[64][33];
  __shared__ float Bs[32][64];
  const int m0 = blockIdx.x * 64;
  const int n0 = blockIdx.y * 64;
  const int tid = threadIdx.x;
  const int tx = tid & 15, ty = tid >> 4;

  float acc[4][4];
#pragma unroll
  for (int i = 0; i < 4; ++i)
#pragma unroll
    for (int j = 0; j < 4; ++j) acc[i][j] = 0.f;

  for (int k0 = 0; k0 < 512; k0 += 32) {
#pragma unroll
    for (int it = 0; it < 2; ++it) {
      int r  = (tid >> 3) + it * 32;
      int kq = (tid & 7) * 4;
      float4 v = *(const float4*)&A[(size_t)(m0 + r) * 512 + k0 + kq];
      As[r][kq + 0] = v.x; As[r][kq + 1] = v.y; As[r][kq + 2] = v.z; As[r][kq + 3] = v.w;
    }
#pragma unroll
    for (int it = 0; it < 2; ++it) {
      int kk = (tid >> 4) + it * 16;
      int nq = (tid & 15) * 4;
      *(float4*)&Bs[kk][nq] = *(const float4*)&Wo[(size_t)(k0 + kk) * 256 + n0 + nq];
    }
    __syncthreads();
#pragma unroll
    for (int kk = 0; kk < 32; ++kk) {
      float a[4], b[4];
#pragma unroll
      for (int i = 0; i < 4; ++i) a[i] = As[ty * 4 + i][kk];
#pragma unroll
      for (int j = 0; j < 4; ++j) b[j] = Bs[kk][tx * 4 + j];
#pragma unroll
      for (int i = 0; i < 4; ++i)
#pragma unroll
        for (int j = 0; j < 4; ++j) acc[i][j] += a[i] * b[j];
    }
    __syncthreads();
  }
#pragma unroll
  for (int i = 0; i < 4; ++i) {
    int m = m0 + ty * 4 + i;
#pragma unroll
    for (int j = 0; j < 4; ++j) {
      int n = n0 + tx * 4 + j;
      out[(size_t)m * 256 + n] = acc[i][j] + bo[n];
    }
  }
}

extern "C" void kernel_launch(void* const* d_in, const int* in_sizes, int n_in,
                              void* d_out, int out_size, void* d_ws, size_t ws_size,
                              hipStream_t stream) {
  const float* x  = (const float*)d_in[0];
  const float* h0 = (const float*)d_in[1];
  const float* c0 = (const float*)d_in[2];
  const float* W  = (const float*)d_in[3];
  const float* U  = (const float*)d_in[4];
  const float* bv = (const float*)d_in[5];
  const float* Wo = (const float*)d_in[6];
  const float* bo = (const float*)d_in[7];
  float* out = (float*)d_out;

  float*    hs   = (float*)d_ws;                       // 64 MB
  float*    hbuf = hs + (size_t)B * T * H;             // 256 KB
  unsigned* ctr  = (unsigned*)(hbuf + 2 * (size_t)B * H);

  hipLaunchKernelGGL(zero_ctr, dim3(1), dim3(256), 0, stream, ctr);
  hipLaunchKernelGGL(lstm_seq, dim3(GB * GC), dim3(THREADS), 0, stream,
                     x, h0, c0, W, U, bv, hs, hbuf, ctr);
  hipLaunchKernelGGL(out_gemm, dim3((B * T) / 64, 256 / 64), dim3(256), 0, stream,
                     hs, Wo, bo, out);
}

// Round 4
// 5820.176 us; speedup vs baseline: 1.7068x; 1.2065x over previous
//
#include <hip/hip_runtime.h>
#include <cstdint>
#include <cstddef>

// LSTM: B=64, T=512, D=128, H=512, O=256.
// Persistent 256-wg kernel: 8 batch-groups x 32 col-groups; each wg owns
// 8 batches x 16 h-cols (64 gate cols).
// KEY (R3): block->(g,cg) remap clusters COL-groups per XCD (4 distinct
// cg x 8 g per XCD with round-robin placement) -> per-XCD weight footprint
// 640 KB, L2-resident. Batch-group barrier spans XCDs (h is tiny, exchanged
// via device-coherent relaxed atomics; counter RMW at coherence point).
// hs written nontemporal, x read nontemporal (read/write-once streams must
// not evict U from L2).  R4: fix nontemporal builtin type (needs native
// ext_vector_type, not HIP_vector_type).
// Workspace: hs f32 64MB + hbuf 256KB + counters.

namespace {
constexpr int B  = 64;
constexpr int T  = 512;
constexpr int D  = 128;
constexpr int H  = 512;
constexpr int G4 = 4 * H;          // 2048
constexpr int GB = 8;              // batch groups
constexpr int GC = 32;             // col groups (barrier participants per group)
constexpr int NB = B / GB;         // 8 batches per wg
constexpr int NC = H / GC;         // 16 h-cols per wg
constexpr int NCC = 4 * NC;        // 64 gate cols per wg
constexpr int THREADS = 256;
constexpr int KS = 16;             // k-splits (each covers 32 of K=512, 8 of D=128)
constexpr int ZSTRIDE = NB * NCC + 4;  // 516, breaks power-of-2 LDS stride
}

typedef float f32x4 __attribute__((ext_vector_type(4)));  // native vec for builtins

__device__ __forceinline__ float sigf(float z) {
  return __fdividef(1.0f, 1.0f + __expf(-z));
}
__device__ __forceinline__ float tanhf_fast(float z) {
  float e = __expf(2.0f * z);
  return 1.0f - __fdividef(2.0f, e + 1.0f);
}

__global__ void zero_ctr(unsigned* __restrict__ c) {
  c[threadIdx.x] = 0u;   // 8 groups at stride 32 u32 (128B apart)
}

__global__ __launch_bounds__(THREADS) void lstm_seq(
    const float* __restrict__ x, const float* __restrict__ h0,
    const float* __restrict__ c0, const float* __restrict__ W,
    const float* __restrict__ U, const float* __restrict__ bias,
    float* __restrict__ hs,      // ws [B][T][H]
    float* __restrict__ hbuf,    // ws [2][B][H]  (coherent h exchange)
    unsigned* __restrict__ ctr)  // ws [8 groups * 32]
{
  const int tid = threadIdx.x;
  // --- XCD-locality remap (heuristic only; correct for any placement) ---
  // round-robin: xcd = blockIdx%8. Give each XCD 4 distinct col-groups
  // shared by all 8 batch-groups -> U/W slices stay L2-resident.
  const int xcd  = blockIdx.x & 7;
  const int slot = blockIdx.x >> 3;        // 0..31
  const int g    = slot & 7;               // batch group (all 8 per XCD)
  const int cg   = xcd * 4 + (slot >> 3);  // col group (4 distinct per XCD)
  const int b0  = g * NB;
  const int hc0 = cg * NC;

  __shared__ float h_lds[NB][H];          // 16 KB
  __shared__ float zpart[KS * ZSTRIDE];   // ~33 KB
  __shared__ float zfull[NB][NCC];        // 2 KB
  __shared__ float c_lds[NB][NC];         // 0.5 KB

  if (tid < NB * NC) {
    int b = tid / NC, hc = tid % NC;
    c_lds[b][hc] = c0[(size_t)(b0 + b) * H + hc0 + hc];
  }

  const int cq  = tid & 15;          // 4 gate cols cc0..cc0+3
  const int ks  = tid >> 4;          // 16 k-splits; k = 64*j + 4*ks + kk
  const int cc0 = cq * 4;
  const int gate  = cc0 >> 4;
  const int gcol0 = gate * H + hc0 + (cc0 & 15);

  // hoisted bias for the reduce phase (thread handles p = 2*tid, 2*tid+1)
  float bias_r[2];
#pragma unroll
  for (int e = 0; e < 2; ++e) {
    int cc = (tid * 2 + e) & 63;
    bias_r[e] = bias[(cc >> 4) * H + hc0 + (cc & 15)];
  }

  unsigned* myctr = ctr + g * 32;

  for (int t = 0; t < T; ++t) {
    // ---- phase A (h-independent): acc init + x_t @ W partials ----
    float acc[NB][4];
#pragma unroll
    for (int b = 0; b < NB; ++b) {
      acc[b][0] = 0.f; acc[b][1] = 0.f; acc[b][2] = 0.f; acc[b][3] = 0.f;
    }
    {
      const float* Wp = W + (size_t)(4 * ks) * G4 + gcol0;
#pragma unroll
      for (int j = 0; j < 2; ++j) {
        const float* Wj = Wp + (size_t)(64 * j) * G4;
        float4 w0 = *(const float4*)(Wj + 0 * (size_t)G4);
        float4 w1 = *(const float4*)(Wj + 1 * (size_t)G4);
        float4 w2 = *(const float4*)(Wj + 2 * (size_t)G4);
        float4 w3 = *(const float4*)(Wj + 3 * (size_t)G4);
        const int db = 64 * j + 4 * ks;
#pragma unroll
        for (int b = 0; b < NB; ++b) {
          f32x4 x4 = __builtin_nontemporal_load(
              (const f32x4*)&x[(((size_t)(b0 + b)) * T + t) * D + db]);
          acc[b][0] += x4.x * w0.x + x4.y * w1.x + x4.z * w2.x + x4.w * w3.x;
          acc[b][1] += x4.x * w0.y + x4.y * w1.y + x4.z * w2.y + x4.w * w3.y;
          acc[b][2] += x4.x * w0.z + x4.y * w1.z + x4.z * w2.z + x4.w * w3.z;
          acc[b][3] += x4.x * w0.w + x4.y * w1.w + x4.z * w2.w + x4.w * w3.w;
        }
      }
    }

    // ---- wait for h(t-1) from the group's 32 wgs (RELAXED polls only) ----
    if (t > 0 && tid == 0) {
      const unsigned target = (unsigned)(GC * t);
      while (__hip_atomic_load(myctr, __ATOMIC_RELAXED, __HIP_MEMORY_SCOPE_AGENT) < target)
        __builtin_amdgcn_s_sleep(1);
      asm volatile("" ::: "memory");  // compiler-only fence; no cache ops
    }
    __syncthreads();

    // ---- stage h(t-1) into LDS (cache-bypassing coherent loads) ----
    if (t == 0) {
      const float4* hsrc = (const float4*)(h0 + (size_t)b0 * H);
#pragma unroll
      for (int i = 0; i < (NB * H / 4) / THREADS; ++i)
        ((float4*)&h_lds[0][0])[tid + i * THREADS] = hsrc[tid + i * THREADS];
    } else {
      const float* src = hbuf + ((size_t)(((t - 1) & 1) * B + b0)) * H;
#pragma unroll
      for (int i = 0; i < NB * H / THREADS; ++i)
        ((float*)&h_lds[0][0])[tid + i * THREADS] =
            __hip_atomic_load(src + tid + i * THREADS,
                              __ATOMIC_RELAXED, __HIP_MEMORY_SCOPE_AGENT);
    }
    __syncthreads();

    // ---- h @ U partials (U slice L2-resident under the XCD remap) ----
    {
      const float* Up = U + (size_t)(4 * ks) * G4 + gcol0;
#pragma unroll
      for (int j = 0; j < 8; ++j) {
        const float* Uj = Up + (size_t)(64 * j) * G4;
        float4 u0 = *(const float4*)(Uj + 0 * (size_t)G4);
        float4 u1 = *(const float4*)(Uj + 1 * (size_t)G4);
        float4 u2 = *(const float4*)(Uj + 2 * (size_t)G4);
        float4 u3 = *(const float4*)(Uj + 3 * (size_t)G4);
        const int kb = 64 * j + 4 * ks;
#pragma unroll
        for (int b = 0; b < NB; ++b) {
          float4 h4 = *(const float4*)&h_lds[b][kb];
          acc[b][0] += h4.x * u0.x + h4.y * u1.x + h4.z * u2.x + h4.w * u3.x;
          acc[b][1] += h4.x * u0.y + h4.y * u1.y + h4.z * u2.y + h4.w * u3.y;
          acc[b][2] += h4.x * u0.z + h4.y * u1.z + h4.z * u2.z + h4.w * u3.z;
          acc[b][3] += h4.x * u0.w + h4.y * u1.w + h4.z * u2.w + h4.w * u3.w;
        }
      }
    }

    // ---- store partials, reduce across 16 k-splits, add bias ----
#pragma unroll
    for (int b = 0; b < NB; ++b)
      *(float4*)&zpart[ks * ZSTRIDE + b * NCC + cc0] =
          make_float4(acc[b][0], acc[b][1], acc[b][2], acc[b][3]);
    __syncthreads();

#pragma unroll
    for (int e = 0; e < 2; ++e) {
      int p  = tid * 2 + e;          // 512 (b,cc) pairs
      int b  = p >> 6, cc = p & 63;
      float s = bias_r[e];
#pragma unroll
      for (int k2 = 0; k2 < KS; ++k2) s += zpart[k2 * ZSTRIDE + b * NCC + cc];
      zfull[b][cc] = s;
    }
    __syncthreads();

    // ---- gates, state update, publish h(t) ----
    if (tid < NB * NC) {
      int b = tid >> 4, hc = tid & 15;
      float zi = zfull[b][hc];
      float zf = zfull[b][NC + hc];
      float zg = zfull[b][2 * NC + hc];
      float zo = zfull[b][3 * NC + hc];
      float ii = sigf(zi), ff = sigf(zf), gg = tanhf_fast(zg), oo = sigf(zo);
      float c  = ff * c_lds[b][hc] + ii * gg;
      c_lds[b][hc] = c;
      float hn = oo * tanhf_fast(c);
      __hip_atomic_store(hbuf + ((size_t)((t & 1) * B + b0 + b)) * H + hc0 + hc,
                         hn, __ATOMIC_RELAXED, __HIP_MEMORY_SCOPE_AGENT);
      // hs is a write-once stream read by the next kernel: keep it out of L2
      __builtin_nontemporal_store(hn, &hs[(((size_t)(b0 + b)) * T + t) * H + hc0 + hc]);
    }
    // ensure THIS wave's h stores reached the coherence point, then barrier
    asm volatile("s_waitcnt vmcnt(0)" ::: "memory");
    __syncthreads();

    // ---- signal h(t) ready (monotonic counter, no fences) ----
    if (tid == 0)
      __hip_atomic_fetch_add(myctr, 1u, __ATOMIC_RELAXED, __HIP_MEMORY_SCOPE_AGENT);
  }
}

// ---- output projection: out[M,256] = hs[M,512] @ Wo[512,256] + bo ----
__global__ __launch_bounds__(256) void out_gemm(
    const float* __restrict__ A, const float* __restrict__ Wo,
    const float* __restrict__ bo, float* __restrict__ out)
{
  __shared__ float As[64][33];
  __shared__ float Bs[32][64];
  const int m0 = blockIdx.x * 64;
  const int n0 = blockIdx.y * 64;
  const int tid = threadIdx.x;
  const int tx = tid & 15, ty = tid >> 4;

  float acc[4][4];
#pragma unroll
  for (int i = 0; i < 4; ++i)
#pragma unroll
    for (int j = 0; j < 4; ++j) acc[i][j] = 0.f;

  for (int k0 = 0; k0 < 512; k0 += 32) {
#pragma unroll
    for (int it = 0; it < 2; ++it) {
      int r  = (tid >> 3) + it * 32;
      int kq = (tid & 7) * 4;
      float4 v = *(const float4*)&A[(size_t)(m0 + r) * 512 + k0 + kq];
      As[r][kq + 0] = v.x; As[r][kq + 1] = v.y; As[r][kq + 2] = v.z; As[r][kq + 3] = v.w;
    }
#pragma unroll
    for (int it = 0; it < 2; ++it) {
      int kk = (tid >> 4) + it * 16;
      int nq = (tid & 15) * 4;
      *(float4*)&Bs[kk][nq] = *(const float4*)&Wo[(size_t)(k0 + kk) * 256 + n0 + nq];
    }
    __syncthreads();
#pragma unroll
    for (int kk = 0; kk < 32; ++kk) {
      float a[4], b[4];
#pragma unroll
      for (int i = 0; i < 4; ++i) a[i] = As[ty * 4 + i][kk];
#pragma unroll
      for (int j = 0; j < 4; ++j) b[j] = Bs[kk][tx * 4 + j];
#pragma unroll
      for (int i = 0; i < 4; ++i)
#pragma unroll
        for (int j = 0; j < 4; ++j) acc[i][j] += a[i] * b[j];
    }
    __syncthreads();
  }
#pragma unroll
  for (int i = 0; i < 4; ++i) {
    int m = m0 + ty * 4 + i;
#pragma unroll
    for (int j = 0; j < 4; ++j) {
      int n = n0 + tx * 4 + j;
      out[(size_t)m * 256 + n] = acc[i][j] + bo[n];
    }
  }
}

extern "C" void kernel_launch(void* const* d_in, const int* in_sizes, int n_in,
                              void* d_out, int out_size, void* d_ws, size_t ws_size,
                              hipStream_t stream) {
  const float* x  = (const float*)d_in[0];
  const float* h0 = (const float*)d_in[1];
  const float* c0 = (const float*)d_in[2];
  const float* W  = (const float*)d_in[3];
  const float* U  = (const float*)d_in[4];
  const float* bv = (const float*)d_in[5];
  const float* Wo = (const float*)d_in[6];
  const float* bo = (const float*)d_in[7];
  float* out = (float*)d_out;

  float*    hs   = (float*)d_ws;                       // 64 MB
  float*    hbuf = hs + (size_t)B * T * H;             // 256 KB
  unsigned* ctr  = (unsigned*)(hbuf + 2 * (size_t)B * H);

  hipLaunchKernelGGL(zero_ctr, dim3(1), dim3(256), 0, stream, ctr);
  hipLaunchKernelGGL(lstm_seq, dim3(GB * GC), dim3(THREADS), 0, stream,
                     x, h0, c0, W, U, bv, hs, hbuf, ctr);
  hipLaunchKernelGGL(out_gemm, dim3((B * T) / 64, 256 / 64), dim3(256), 0, stream,
                     hs, Wo, bo, out);
}

// Round 5
// 4900.800 us; speedup vs baseline: 2.0270x; 1.1876x over previous
//
#include <hip/hip_runtime.h>
#include <cstdint>
#include <cstddef>

// LSTM: B=64, T=512, D=128, H=512, O=256.
// Persistent 512-wg kernel (2 wgs/CU): 16 batch-groups x 32 col-groups; each
// wg owns 4 batches x 16 h-cols (64 gate cols).
// R5: 2 wgs/CU for latency hiding (LDS 26KB, launch_bounds(256,2));
// U j=0..1 register-prefetched ABOVE the spin (asm fence was blocking
// hoisting of h-independent loads); h staged via 8B relaxed-atomic loads;
// x uses normal cached loads (4x L2 reuse per XCD).
// XCD remap: per XCD 4 distinct col-groups x 16 batch-groups -> 640KB
// weight footprint, L2-resident. Barrier: per-batch-group monotonic counter,
// RELAXED polls only (no cache-invalidating fences anywhere).
// Workspace: hs f32 64MB + hbuf 256KB + ctr 2KB.

namespace {
constexpr int B  = 64;
constexpr int T  = 512;
constexpr int D  = 128;
constexpr int H  = 512;
constexpr int G4 = 4 * H;          // 2048
constexpr int GB = 16;             // batch groups
constexpr int GC = 32;             // col groups (barrier participants per group)
constexpr int NB = B / GB;         // 4 batches per wg
constexpr int NC = H / GC;         // 16 h-cols per wg
constexpr int NCC = 4 * NC;        // 64 gate cols per wg
constexpr int THREADS = 256;
constexpr int KS = 16;             // k-splits (each covers 32 of K=512, 8 of D=128)
constexpr int ZSTRIDE = NB * NCC + 4;  // 260, breaks power-of-2 LDS stride
}

typedef float f32x4 __attribute__((ext_vector_type(4)));

__device__ __forceinline__ float sigf(float z) {
  return __fdividef(1.0f, 1.0f + __expf(-z));
}
__device__ __forceinline__ float tanhf_fast(float z) {
  float e = __expf(2.0f * z);
  return 1.0f - __fdividef(2.0f, e + 1.0f);
}

__global__ void zero_ctr(unsigned* __restrict__ c) {
  c[threadIdx.x] = 0u;
  c[threadIdx.x + 256] = 0u;   // 16 groups at stride 32 u32 (128B apart)
}

__global__ __launch_bounds__(THREADS, 2) void lstm_seq(
    const float* __restrict__ x, const float* __restrict__ h0,
    const float* __restrict__ c0, const float* __restrict__ W,
    const float* __restrict__ U, const float* __restrict__ bias,
    float* __restrict__ hs,      // ws [B][T][H]
    float* __restrict__ hbuf,    // ws [2][B][H]  (coherent h exchange)
    unsigned* __restrict__ ctr)  // ws [16 groups * 32]
{
  const int tid = threadIdx.x;
  // --- XCD-locality remap (heuristic; correct for any placement) ---
  // round-robin xcd = blockIdx%8; per XCD: 4 distinct col-groups x 16 batch
  // groups -> U/W slice footprint 640KB, L2-resident.
  const int xcd  = blockIdx.x & 7;
  const int slot = blockIdx.x >> 3;        // 0..63
  const int g    = slot & 15;              // batch group (all 16 per XCD)
  const int cg   = xcd * 4 + (slot >> 4);  // col group (4 distinct per XCD)
  const int b0  = g * NB;
  const int hc0 = cg * NC;

  __shared__ float h_lds[NB][H];          // 8 KB
  __shared__ float zpart[KS * ZSTRIDE];   // 16.6 KB
  __shared__ float zfull[NB][NCC];        // 1 KB
  __shared__ float c_lds[NB][NC];         // 256 B

  if (tid < NB * NC) {
    int b = tid / NC, hc = tid % NC;
    c_lds[b][hc] = c0[(size_t)(b0 + b) * H + hc0 + hc];
  }

  const int cq  = tid & 15;          // 4 gate cols cc0..cc0+3
  const int ks  = tid >> 4;          // 16 k-splits; k = 64*j + 4*ks + kk
  const int cc0 = cq * 4;
  const int gate  = cc0 >> 4;
  const int gcol0 = gate * H + hc0 + (cc0 & 15);

  // hoisted bias for the reduce phase (thread handles pair p = tid)
  const int rcc = tid & 63;
  const float bias_r = bias[(rcc >> 4) * H + hc0 + (rcc & 15)];

  unsigned* myctr = ctr + g * 32;

  for (int t = 0; t < T; ++t) {
    // ---- phase A (h-independent): acc init + x_t @ W partials ----
    float acc[NB][4];
#pragma unroll
    for (int b = 0; b < NB; ++b) {
      acc[b][0] = 0.f; acc[b][1] = 0.f; acc[b][2] = 0.f; acc[b][3] = 0.f;
    }
    {
      const float* Wp = W + (size_t)(4 * ks) * G4 + gcol0;
#pragma unroll
      for (int j = 0; j < 2; ++j) {
        const float* Wj = Wp + (size_t)(64 * j) * G4;
        f32x4 w0 = *(const f32x4*)(Wj + 0 * (size_t)G4);
        f32x4 w1 = *(const f32x4*)(Wj + 1 * (size_t)G4);
        f32x4 w2 = *(const f32x4*)(Wj + 2 * (size_t)G4);
        f32x4 w3 = *(const f32x4*)(Wj + 3 * (size_t)G4);
        const int db = 64 * j + 4 * ks;
#pragma unroll
        for (int b = 0; b < NB; ++b) {
          f32x4 x4 = *(const f32x4*)&x[(((size_t)(b0 + b)) * T + t) * D + db];
          acc[b][0] += x4.x * w0.x + x4.y * w1.x + x4.z * w2.x + x4.w * w3.x;
          acc[b][1] += x4.x * w0.y + x4.y * w1.y + x4.z * w2.y + x4.w * w3.y;
          acc[b][2] += x4.x * w0.z + x4.y * w1.z + x4.z * w2.z + x4.w * w3.z;
          acc[b][3] += x4.x * w0.w + x4.y * w1.w + x4.z * w2.w + x4.w * w3.w;
        }
      }
    }

    // ---- U register prefetch (h-independent; issued BEFORE the spin) ----
    f32x4 upf0[4], upf1[4];
    {
      const float* Up = U + (size_t)(4 * ks) * G4 + gcol0;
#pragma unroll
      for (int r = 0; r < 4; ++r)
        upf0[r] = *(const f32x4*)(Up + (size_t)r * G4);
      const float* U1 = Up + (size_t)64 * G4;
#pragma unroll
      for (int r = 0; r < 4; ++r)
        upf1[r] = *(const f32x4*)(U1 + (size_t)r * G4);
    }

    // ---- wait for h(t-1) from the group's 32 wgs (RELAXED polls only) ----
    if (t > 0 && tid == 0) {
      const unsigned target = (unsigned)(GC * t);
      while (__hip_atomic_load(myctr, __ATOMIC_RELAXED, __HIP_MEMORY_SCOPE_AGENT) < target)
        __builtin_amdgcn_s_sleep(1);
      asm volatile("" ::: "memory");  // compiler-only fence; no cache ops
    }
    __syncthreads();

    // ---- stage h(t-1) into LDS (8B cache-bypassing coherent loads) ----
    if (t == 0) {
      const f32x4* hsrc = (const f32x4*)(h0 + (size_t)b0 * H);
#pragma unroll
      for (int i = 0; i < (NB * H / 4) / THREADS; ++i)
        ((f32x4*)&h_lds[0][0])[tid + i * THREADS] = hsrc[tid + i * THREADS];
    } else {
      const unsigned long long* src = (const unsigned long long*)
          (hbuf + ((size_t)(((t - 1) & 1) * B + b0)) * H);
#pragma unroll
      for (int i = 0; i < (NB * H / 2) / THREADS; ++i)   // 4 x 8B per thread
        ((unsigned long long*)&h_lds[0][0])[tid + i * THREADS] =
            __hip_atomic_load(src + tid + i * THREADS,
                              __ATOMIC_RELAXED, __HIP_MEMORY_SCOPE_AGENT);
    }
    __syncthreads();

    // ---- h @ U partials (j=0,1 from prefetched regs) ----
    {
      const float* Up = U + (size_t)(4 * ks) * G4 + gcol0;
#pragma unroll
      for (int j = 0; j < 8; ++j) {
        f32x4 u0, u1, u2, u3;
        if (j == 0) { u0 = upf0[0]; u1 = upf0[1]; u2 = upf0[2]; u3 = upf0[3]; }
        else if (j == 1) { u0 = upf1[0]; u1 = upf1[1]; u2 = upf1[2]; u3 = upf1[3]; }
        else {
          const float* Uj = Up + (size_t)(64 * j) * G4;
          u0 = *(const f32x4*)(Uj + 0 * (size_t)G4);
          u1 = *(const f32x4*)(Uj + 1 * (size_t)G4);
          u2 = *(const f32x4*)(Uj + 2 * (size_t)G4);
          u3 = *(const f32x4*)(Uj + 3 * (size_t)G4);
        }
        const int kb = 64 * j + 4 * ks;
#pragma unroll
        for (int b = 0; b < NB; ++b) {
          f32x4 h4 = *(const f32x4*)&h_lds[b][kb];
          acc[b][0] += h4.x * u0.x + h4.y * u1.x + h4.z * u2.x + h4.w * u3.x;
          acc[b][1] += h4.x * u0.y + h4.y * u1.y + h4.z * u2.y + h4.w * u3.y;
          acc[b][2] += h4.x * u0.z + h4.y * u1.z + h4.z * u2.z + h4.w * u3.z;
          acc[b][3] += h4.x * u0.w + h4.y * u1.w + h4.z * u2.w + h4.w * u3.w;
        }
      }
    }

    // ---- store partials, reduce across 16 k-splits, add bias ----
#pragma unroll
    for (int b = 0; b < NB; ++b)
      *(f32x4*)&zpart[ks * ZSTRIDE + b * NCC + cc0] =
          (f32x4){acc[b][0], acc[b][1], acc[b][2], acc[b][3]};
    __syncthreads();

    {
      int b = tid >> 6, cc = tid & 63;     // 256 (b,cc) pairs, 1 per thread
      float s = bias_r;
#pragma unroll
      for (int k2 = 0; k2 < KS; ++k2) s += zpart[k2 * ZSTRIDE + b * NCC + cc];
      zfull[b][cc] = s;
    }
    __syncthreads();

    // ---- gates, state update, publish h(t) ----
    if (tid < NB * NC) {
      int b = tid >> 4, hc = tid & 15;
      float zi = zfull[b][hc];
      float zf = zfull[b][NC + hc];
      float zg = zfull[b][2 * NC + hc];
      float zo = zfull[b][3 * NC + hc];
      float ii = sigf(zi), ff = sigf(zf), gg = tanhf_fast(zg), oo = sigf(zo);
      float c  = ff * c_lds[b][hc] + ii * gg;
      c_lds[b][hc] = c;
      float hn = oo * tanhf_fast(c);
      __hip_atomic_store(hbuf + ((size_t)((t & 1) * B + b0 + b)) * H + hc0 + hc,
                         hn, __ATOMIC_RELAXED, __HIP_MEMORY_SCOPE_AGENT);
      // hs is a write-once stream read by the next kernel: keep it out of L2
      __builtin_nontemporal_store(hn, &hs[(((size_t)(b0 + b)) * T + t) * H + hc0 + hc]);
    }
    // ensure THIS wave's h stores reached the coherence point, then barrier
    asm volatile("s_waitcnt vmcnt(0)" ::: "memory");
    __syncthreads();

    // ---- signal h(t) ready (monotonic counter, no fences) ----
    if (tid == 0)
      __hip_atomic_fetch_add(myctr, 1u, __ATOMIC_RELAXED, __HIP_MEMORY_SCOPE_AGENT);
  }
}

// ---- output projection: out[M,256] = hs[M,512] @ Wo[512,256] + bo ----
__global__ __launch_bounds__(256) void out_gemm(
    const float* __restrict__ A, const float* __restrict__ Wo,
    const float* __restrict__ bo, float* __restrict__ out)
{
  __shared__ float As[64][33];
  __shared__ float Bs[32][64];
  const int m0 = blockIdx.x * 64;
  const int n0 = blockIdx.y * 64;
  const int tid = threadIdx.x;
  const int tx = tid & 15, ty = tid >> 4;

  float acc[4][4];
#pragma unroll
  for (int i = 0; i < 4; ++i)
#pragma unroll
    for (int j = 0; j < 4; ++j) acc[i][j] = 0.f;

  for (int k0 = 0; k0 < 512; k0 += 32) {
#pragma unroll
    for (int it = 0; it < 2; ++it) {
      int r  = (tid >> 3) + it * 32;
      int kq = (tid & 7) * 4;
      float4 v = *(const float4*)&A[(size_t)(m0 + r) * 512 + k0 + kq];
      As[r][kq + 0] = v.x; As[r][kq + 1] = v.y; As[r][kq + 2] = v.z; As[r][kq + 3] = v.w;
    }
#pragma unroll
    for (int it = 0; it < 2; ++it) {
      int kk = (tid >> 4) + it * 16;
      int nq = (tid & 15) * 4;
      *(float4*)&Bs[kk][nq] = *(const float4*)&Wo[(size_t)(k0 + kk) * 256 + n0 + nq];
    }
    __syncthreads();
#pragma unroll
    for (int kk = 0; kk < 32; ++kk) {
      float a[4], b[4];
#pragma unroll
      for (int i = 0; i < 4; ++i) a[i] = As[ty * 4 + i][kk];
#pragma unroll
      for (int j = 0; j < 4; ++j) b[j] = Bs[kk][tx * 4 + j];
#pragma unroll
      for (int i = 0; i < 4; ++i)
#pragma unroll
        for (int j = 0; j < 4; ++j) acc[i][j] += a[i] * b[j];
    }
    __syncthreads();
  }
#pragma unroll
  for (int i = 0; i < 4; ++i) {
    int m = m0 + ty * 4 + i;
#pragma unroll
    for (int j = 0; j < 4; ++j) {
      int n = n0 + tx * 4 + j;
      out[(size_t)m * 256 + n] = acc[i][j] + bo[n];
    }
  }
}

extern "C" void kernel_launch(void* const* d_in, const int* in_sizes, int n_in,
                              void* d_out, int out_size, void* d_ws, size_t ws_size,
                              hipStream_t stream) {
  const float* x  = (const float*)d_in[0];
  const float* h0 = (const float*)d_in[1];
  const float* c0 = (const float*)d_in[2];
  const float* W  = (const float*)d_in[3];
  const float* U  = (const float*)d_in[4];
  const float* bv = (const float*)d_in[5];
  const float* Wo = (const float*)d_in[6];
  const float* bo = (const float*)d_in[7];
  float* out = (float*)d_out;

  float*    hs   = (float*)d_ws;                       // 64 MB
  float*    hbuf = hs + (size_t)B * T * H;             // 256 KB
  unsigned* ctr  = (unsigned*)(hbuf + 2 * (size_t)B * H);

  hipLaunchKernelGGL(zero_ctr, dim3(1), dim3(256), 0, stream, ctr);
  hipLaunchKernelGGL(lstm_seq, dim3(GB * GC), dim3(THREADS), 0, stream,
                     x, h0, c0, W, U, bv, hs, hbuf, ctr);
  hipLaunchKernelGGL(out_gemm, dim3((B * T) / 64, 256 / 64), dim3(256), 0, stream,
                     hs, Wo, bo, out);
}

// Round 6
// 4109.551 us; speedup vs baseline: 2.4173x; 1.1925x over previous
//
#include <hip/hip_runtime.h>
#include <cstdint>
#include <cstddef>

// LSTM: B=64, T=512, D=128, H=512, O=256.
// Persistent 512-wg kernel (2 wgs/CU): 16 batch-groups x 32 col-groups; each
// wg owns 4 batches x 16 h-cols (64 gate cols).
// R6: per-wg FLAG-ARRAY barrier (kills the 32-way same-address RMW serial
// chain of the counter barrier); 6/8 U j-blocks + next-step x@W prefetched
// into registers AFTER signaling / BEFORE spinning -> post-barrier path is
// h-stage + pure-register FMA; activations spread over all 256 threads.
// XCD remap: per XCD 4 distinct col-groups x 16 batch-groups -> 640KB weight
// footprint, L2-resident. All h/flag traffic via relaxed AGENT atomics (no
// cache-invalidating fences anywhere).
// Workspace: hs f32 64MB + hbuf 256KB + flags 2KB.

namespace {
constexpr int B  = 64;
constexpr int T  = 512;
constexpr int D  = 128;
constexpr int H  = 512;
constexpr int G4 = 4 * H;          // 2048
constexpr int GB = 16;             // batch groups
constexpr int GC = 32;             // col groups (barrier participants per group)
constexpr int NB = B / GB;         // 4 batches per wg
constexpr int NC = H / GC;         // 16 h-cols per wg
constexpr int NCC = 4 * NC;        // 64 gate cols per wg
constexpr int THREADS = 256;
constexpr int KS = 16;             // k-splits (each covers 32 of K=512, 8 of D=128)
constexpr int NPF = 6;             // U j-blocks prefetched into VGPRs
constexpr int ZSTRIDE = NB * NCC + 4;  // 260, breaks power-of-2 LDS stride
}

typedef float f32x4 __attribute__((ext_vector_type(4)));

__device__ __forceinline__ float sigf(float z) {
  return __fdividef(1.0f, 1.0f + __expf(-z));
}
__device__ __forceinline__ float tanhf_fast(float z) {
  float e = __expf(2.0f * z);
  return 1.0f - __fdividef(2.0f, e + 1.0f);
}

__global__ void zero_ctr(unsigned* __restrict__ c) {
  c[threadIdx.x] = 0u;
  c[threadIdx.x + 256] = 0u;   // covers 16*32 flags
}

__global__ __launch_bounds__(THREADS, 2) void lstm_seq(
    const float* __restrict__ x, const float* __restrict__ h0,
    const float* __restrict__ c0, const float* __restrict__ W,
    const float* __restrict__ U, const float* __restrict__ bias,
    float* __restrict__ hs,      // ws [B][T][H]
    float* __restrict__ hbuf,    // ws [2][B][H]  (coherent h exchange)
    unsigned* __restrict__ flags)// ws [16 groups][32 cg]
{
  const int tid = threadIdx.x;
  // --- XCD-locality remap (heuristic; correct for any placement) ---
  const int xcd  = blockIdx.x & 7;
  const int slot = blockIdx.x >> 3;        // 0..63
  const int g    = slot & 15;              // batch group (all 16 per XCD)
  const int cg   = xcd * 4 + (slot >> 4);  // col group (4 distinct per XCD)
  const int b0  = g * NB;
  const int hc0 = cg * NC;

  __shared__ float h_lds[NB][H];          // 8 KB
  __shared__ float zpart[KS * ZSTRIDE];   // 16.6 KB
  __shared__ float zfull[NB][NCC];        // 1 KB
  __shared__ float c_lds[NB][NC];         // 256 B

  if (tid < NB * NC) {
    int b = tid >> 4, hc = tid & 15;
    c_lds[b][hc] = c0[(size_t)(b0 + b) * H + hc0 + hc];
  }

  const int cq  = tid & 15;          // 4 gate cols cc0..cc0+3
  const int ks  = tid >> 4;          // 16 k-splits; k = 64*j + 4*ks + kk
  const int cc0 = cq * 4;
  const int gate  = cc0 >> 4;
  const int gcol0 = gate * H + hc0 + (cc0 & 15);

  // reduce-phase constants: this thread owns (rb, rcc)
  const int rb  = tid >> 6;
  const int rcc = tid & 63;
  const int rgate = rcc >> 4;
  const float bias_r = bias[rgate * H + hc0 + (rcc & 15)];

  unsigned* myflags = flags + g * 32;
  const float* Up = U + (size_t)(4 * ks) * G4 + gcol0;
  const float* Wp = W + (size_t)(4 * ks) * G4 + gcol0;

  // ---- persistent register state across the barrier ----
  float acc[NB][4];          // x@W partials for the upcoming step
  f32x4 upf[NPF][4];         // U j=0..5 rows for this thread's k-slice

  // prefetch helper (pure register writes; x/W/U loads)
  auto prefetch = [&](int tt) {
#pragma unroll
    for (int b = 0; b < NB; ++b) {
      acc[b][0] = 0.f; acc[b][1] = 0.f; acc[b][2] = 0.f; acc[b][3] = 0.f;
    }
#pragma unroll
    for (int j = 0; j < 2; ++j) {
      const float* Wj = Wp + (size_t)(64 * j) * G4;
      f32x4 w0 = *(const f32x4*)(Wj + 0 * (size_t)G4);
      f32x4 w1 = *(const f32x4*)(Wj + 1 * (size_t)G4);
      f32x4 w2 = *(const f32x4*)(Wj + 2 * (size_t)G4);
      f32x4 w3 = *(const f32x4*)(Wj + 3 * (size_t)G4);
      const int db = 64 * j + 4 * ks;
#pragma unroll
      for (int b = 0; b < NB; ++b) {
        f32x4 x4 = *(const f32x4*)&x[(((size_t)(b0 + b)) * T + tt) * D + db];
        acc[b][0] += x4.x * w0.x + x4.y * w1.x + x4.z * w2.x + x4.w * w3.x;
        acc[b][1] += x4.x * w0.y + x4.y * w1.y + x4.z * w2.y + x4.w * w3.y;
        acc[b][2] += x4.x * w0.z + x4.y * w1.z + x4.z * w2.z + x4.w * w3.z;
        acc[b][3] += x4.x * w0.w + x4.y * w1.w + x4.z * w2.w + x4.w * w3.w;
      }
    }
#pragma unroll
    for (int j = 0; j < NPF; ++j) {
      const float* Uj = Up + (size_t)(64 * j) * G4;
#pragma unroll
      for (int r = 0; r < 4; ++r)
        upf[j][r] = *(const f32x4*)(Uj + (size_t)r * G4);
    }
  };

  prefetch(0);

  for (int t = 0; t < T; ++t) {
    // ---- wait for h(t-1): 64 lanes each watch one flag ----
    if (t > 0) {
      if (tid < 64) {
        const unsigned target = (unsigned)t;
        const unsigned* fl = myflags + (tid & 31);
        while (__hip_atomic_load(fl, __ATOMIC_RELAXED, __HIP_MEMORY_SCOPE_AGENT) < target)
          __builtin_amdgcn_s_sleep(1);
        asm volatile("" ::: "memory");
      }
      __syncthreads();   // release other waves only after flags confirmed
      const unsigned long long* src = (const unsigned long long*)
          (hbuf + ((size_t)(((t - 1) & 1) * B + b0)) * H);
#pragma unroll
      for (int i = 0; i < (NB * H / 2) / THREADS; ++i)   // 4 x 8B per thread
        ((unsigned long long*)&h_lds[0][0])[tid + i * THREADS] =
            __hip_atomic_load(src + tid + i * THREADS,
                              __ATOMIC_RELAXED, __HIP_MEMORY_SCOPE_AGENT);
    } else {
      const f32x4* hsrc = (const f32x4*)(h0 + (size_t)b0 * H);
#pragma unroll
      for (int i = 0; i < (NB * H / 4) / THREADS; ++i)
        ((f32x4*)&h_lds[0][0])[tid + i * THREADS] = hsrc[tid + i * THREADS];
    }
    __syncthreads();

    // ---- issue j=6,7 U loads (L2 hits; complete under the FMA stream) ----
    f32x4 u6[4], u7[4];
#pragma unroll
    for (int r = 0; r < 4; ++r) {
      u6[r] = *(const f32x4*)(Up + (size_t)(64 * 6 + r) * G4);
      u7[r] = *(const f32x4*)(Up + (size_t)(64 * 7 + r) * G4);
    }

    // ---- h @ U: j=0..5 pure-register, then j=6,7 ----
#pragma unroll
    for (int j = 0; j < 8; ++j) {
      f32x4 u0, u1, u2, u3;
      if (j < NPF) { u0 = upf[j][0]; u1 = upf[j][1]; u2 = upf[j][2]; u3 = upf[j][3]; }
      else if (j == 6) { u0 = u6[0]; u1 = u6[1]; u2 = u6[2]; u3 = u6[3]; }
      else { u0 = u7[0]; u1 = u7[1]; u2 = u7[2]; u3 = u7[3]; }
      const int kb = 64 * j + 4 * ks;
#pragma unroll
      for (int b = 0; b < NB; ++b) {
        f32x4 h4 = *(const f32x4*)&h_lds[b][kb];
        acc[b][0] += h4.x * u0.x + h4.y * u1.x + h4.z * u2.x + h4.w * u3.x;
        acc[b][1] += h4.x * u0.y + h4.y * u1.y + h4.z * u2.y + h4.w * u3.y;
        acc[b][2] += h4.x * u0.z + h4.y * u1.z + h4.z * u2.z + h4.w * u3.z;
        acc[b][3] += h4.x * u0.w + h4.y * u1.w + h4.z * u2.w + h4.w * u3.w;
      }
    }

    // ---- store partials, reduce across 16 k-splits, activation ----
#pragma unroll
    for (int b = 0; b < NB; ++b)
      *(f32x4*)&zpart[ks * ZSTRIDE + b * NCC + cc0] =
          (f32x4){acc[b][0], acc[b][1], acc[b][2], acc[b][3]};
    __syncthreads();

    {
      float s = bias_r;
#pragma unroll
      for (int k2 = 0; k2 < KS; ++k2) s += zpart[k2 * ZSTRIDE + rb * NCC + rcc];
      zfull[rb][rcc] = (rgate == 2) ? tanhf_fast(s) : sigf(s);
    }
    __syncthreads();

    // ---- c/h update, publish h(t) ----
    if (tid < NB * NC) {
      int b = tid >> 4, hc = tid & 15;
      float ii = zfull[b][hc];
      float ff = zfull[b][NC + hc];
      float gg = zfull[b][2 * NC + hc];
      float oo = zfull[b][3 * NC + hc];
      float c  = ff * c_lds[b][hc] + ii * gg;
      c_lds[b][hc] = c;
      float hn = oo * tanhf_fast(c);
      __hip_atomic_store(hbuf + ((size_t)((t & 1) * B + b0 + b)) * H + hc0 + hc,
                         hn, __ATOMIC_RELAXED, __HIP_MEMORY_SCOPE_AGENT);
      __builtin_nontemporal_store(hn, &hs[(((size_t)(b0 + b)) * T + t) * H + hc0 + hc]);
    }
    // h stores at coherence point before signaling
    asm volatile("s_waitcnt vmcnt(0)" ::: "memory");
    __syncthreads();

    // ---- signal h(t) ready (one independent store per wg) ----
    if (tid == 0)
      __hip_atomic_store(myflags + cg, (unsigned)(t + 1),
                         __ATOMIC_RELAXED, __HIP_MEMORY_SCOPE_AGENT);

    // ---- prefetch next step (after signaling, before spinning) ----
    prefetch(t + 1 < T ? t + 1 : T - 1);
  }
}

// ---- output projection: out[M,256] = hs[M,512] @ Wo[512,256] + bo ----
__global__ __launch_bounds__(256) void out_gemm(
    const float* __restrict__ A, const float* __restrict__ Wo,
    const float* __restrict__ bo, float* __restrict__ out)
{
  __shared__ float As[64][33];
  __shared__ float Bs[32][64];
  const int m0 = blockIdx.x * 64;
  const int n0 = blockIdx.y * 64;
  const int tid = threadIdx.x;
  const int tx = tid & 15, ty = tid >> 4;

  float acc[4][4];
#pragma unroll
  for (int i = 0; i < 4; ++i)
#pragma unroll
    for (int j = 0; j < 4; ++j) acc[i][j] = 0.f;

  for (int k0 = 0; k0 < 512; k0 += 32) {
#pragma unroll
    for (int it = 0; it < 2; ++it) {
      int r  = (tid >> 3) + it * 32;
      int kq = (tid & 7) * 4;
      float4 v = *(const float4*)&A[(size_t)(m0 + r) * 512 + k0 + kq];
      As[r][kq + 0] = v.x; As[r][kq + 1] = v.y; As[r][kq + 2] = v.z; As[r][kq + 3] = v.w;
    }
#pragma unroll
    for (int it = 0; it < 2; ++it) {
      int kk = (tid >> 4) + it * 16;
      int nq = (tid & 15) * 4;
      *(float4*)&Bs[kk][nq] = *(const float4*)&Wo[(size_t)(k0 + kk) * 256 + n0 + nq];
    }
    __syncthreads();
#pragma unroll
    for (int kk = 0; kk < 32; ++kk) {
      float a[4], b[4];
#pragma unroll
      for (int i = 0; i < 4; ++i) a[i] = As[ty * 4 + i][kk];
#pragma unroll
      for (int j = 0; j < 4; ++j) b[j] = Bs[kk][tx * 4 + j];
#pragma unroll
      for (int i = 0; i < 4; ++i)
#pragma unroll
        for (int j = 0; j < 4; ++j) acc[i][j] += a[i] * b[j];
    }
    __syncthreads();
  }
#pragma unroll
  for (int i = 0; i < 4; ++i) {
    int m = m0 + ty * 4 + i;
#pragma unroll
    for (int j = 0; j < 4; ++j) {
      int n = n0 + tx * 4 + j;
      out[(size_t)m * 256 + n] = acc[i][j] + bo[n];
    }
  }
}

extern "C" void kernel_launch(void* const* d_in, const int* in_sizes, int n_in,
                              void* d_out, int out_size, void* d_ws, size_t ws_size,
                              hipStream_t stream) {
  const float* x  = (const float*)d_in[0];
  const float* h0 = (const float*)d_in[1];
  const float* c0 = (const float*)d_in[2];
  const float* W  = (const float*)d_in[3];
  const float* U  = (const float*)d_in[4];
  const float* bv = (const float*)d_in[5];
  const float* Wo = (const float*)d_in[6];
  const float* bo = (const float*)d_in[7];
  float* out = (float*)d_out;

  float*    hs   = (float*)d_ws;                       // 64 MB
  float*    hbuf = hs + (size_t)B * T * H;             // 256 KB
  unsigned* ctr  = (unsigned*)(hbuf + 2 * (size_t)B * H);

  hipLaunchKernelGGL(zero_ctr, dim3(1), dim3(256), 0, stream, ctr);
  hipLaunchKernelGGL(lstm_seq, dim3(GB * GC), dim3(THREADS), 0, stream,
                     x, h0, c0, W, U, bv, hs, hbuf, ctr);
  hipLaunchKernelGGL(out_gemm, dim3((B * T) / 64, 256 / 64), dim3(256), 0, stream,
                     hs, Wo, bo, out);
}

// Round 7
// 3118.967 us; speedup vs baseline: 3.1850x; 1.3176x over previous
//
#include <hip/hip_runtime.h>
#include <cstdint>
#include <cstddef>

// LSTM: B=64, T=512, D=128, H=512, O=256.
// Persistent 512-wg kernel (2 wgs/CU): 16 batch-groups x 32 col-groups; each
// wg owns 4 batches x 16 h-cols (64 gate cols).
// R7: (1) co-resident wgs now belong to DIFFERENT batch groups (g depends on
// blk>>8) -> independent barrier chains overlap on each CU; (2) signal fast
// path: wave0 h-store -> vmcnt(0) -> flag (hs stream store AFTER flag, no
// syncthreads on the signal path); (3) packed-f32 FMA (f32x2 ops ->
// v_pk_fma_f32, 2x f32 rate).
// XCD remap: per XCD 4 distinct col-groups x 16 batch-groups -> 640KB weight
// footprint, L2-resident. h/flag via relaxed AGENT atomics (no cache-
// invalidating fences anywhere).
// Workspace: hs f32 64MB + hbuf 256KB + flags 2KB.

namespace {
constexpr int B  = 64;
constexpr int T  = 512;
constexpr int D  = 128;
constexpr int H  = 512;
constexpr int G4 = 4 * H;          // 2048
constexpr int GB = 16;             // batch groups
constexpr int GC = 32;             // col groups (barrier participants per group)
constexpr int NB = B / GB;         // 4 batches per wg
constexpr int NC = H / GC;         // 16 h-cols per wg
constexpr int NCC = 4 * NC;        // 64 gate cols per wg
constexpr int THREADS = 256;
constexpr int KS = 16;             // k-splits (each covers 32 of K=512, 8 of D=128)
constexpr int NPF = 6;             // U j-blocks prefetched into VGPRs
constexpr int ZSTRIDE = NB * NCC + 4;  // 260, breaks power-of-2 LDS stride
}

typedef float f32x4 __attribute__((ext_vector_type(4)));
typedef float f32x2 __attribute__((ext_vector_type(2)));

__device__ __forceinline__ float sigf(float z) {
  return __fdividef(1.0f, 1.0f + __expf(-z));
}
__device__ __forceinline__ float tanhf_fast(float z) {
  float e = __expf(2.0f * z);
  return 1.0f - __fdividef(2.0f, e + 1.0f);
}

__global__ void zero_ctr(unsigned* __restrict__ c) {
  c[threadIdx.x] = 0u;
  c[threadIdx.x + 256] = 0u;   // covers 16*32 flags
}

__global__ __launch_bounds__(THREADS, 2) void lstm_seq(
    const float* __restrict__ x, const float* __restrict__ h0,
    const float* __restrict__ c0, const float* __restrict__ W,
    const float* __restrict__ U, const float* __restrict__ bias,
    float* __restrict__ hs,      // ws [B][T][H]
    float* __restrict__ hbuf,    // ws [2][B][H]  (coherent h exchange)
    unsigned* __restrict__ flags)// ws [16 groups][32 cg]
{
  const int tid = threadIdx.x;
  // --- XCD-locality remap + co-residency decorrelation ---
  // xcd = blk&7 (round-robin heuristic). v in [0,32) picks (cg-offset, g&7).
  // p = blk>>8 picks the batch-group HALF: blockIdx i and i+256 (the two wgs
  // co-resident on one CU under round-robin) get DIFFERENT batch groups ->
  // independent barrier chains overlap. Per XCD: 4 distinct col-groups.
  const int xcd = blockIdx.x & 7;
  const int v   = (blockIdx.x >> 3) & 31;
  const int p   = blockIdx.x >> 8;
  const int g   = (v & 7) + 8 * p;
  const int cg  = xcd * 4 + (v >> 3);
  const int b0  = g * NB;
  const int hc0 = cg * NC;

  __shared__ float h_lds[NB][H];          // 8 KB
  __shared__ float zpart[KS * ZSTRIDE];   // 16.6 KB
  __shared__ float zfull[NB][NCC];        // 1 KB
  __shared__ float c_lds[NB][NC];         // 256 B

  if (tid < NB * NC) {
    int b = tid >> 4, hc = tid & 15;
    c_lds[b][hc] = c0[(size_t)(b0 + b) * H + hc0 + hc];
  }

  const int cq  = tid & 15;          // 4 gate cols cc0..cc0+3
  const int ks  = tid >> 4;          // 16 k-splits; k = 64*j + 4*ks + kk
  const int cc0 = cq * 4;
  const int gate  = cc0 >> 4;
  const int gcol0 = gate * H + hc0 + (cc0 & 15);

  // reduce-phase constants: this thread owns (rb, rcc)
  const int rb  = tid >> 6;
  const int rcc = tid & 63;
  const int rgate = rcc >> 4;
  const float bias_r = bias[rgate * H + hc0 + (rcc & 15)];

  unsigned* myflags = flags + g * 32;
  const float* Up = U + (size_t)(4 * ks) * G4 + gcol0;
  const float* Wp = W + (size_t)(4 * ks) * G4 + gcol0;

  // ---- persistent register state across the barrier ----
  f32x2 acc2[NB][2];         // z partials (packed pairs of gate cols)
  f32x4 upf[NPF][4];         // U j=0..NPF-1 rows for this thread's k-slice

  auto prefetch = [&](int tt) {
#pragma unroll
    for (int b = 0; b < NB; ++b) { acc2[b][0] = 0.f; acc2[b][1] = 0.f; }
#pragma unroll
    for (int j = 0; j < 2; ++j) {
      const float* Wj = Wp + (size_t)(64 * j) * G4;
      f32x4 w0 = *(const f32x4*)(Wj + 0 * (size_t)G4);
      f32x4 w1 = *(const f32x4*)(Wj + 1 * (size_t)G4);
      f32x4 w2 = *(const f32x4*)(Wj + 2 * (size_t)G4);
      f32x4 w3 = *(const f32x4*)(Wj + 3 * (size_t)G4);
      const int db = 64 * j + 4 * ks;
#pragma unroll
      for (int b = 0; b < NB; ++b) {
        f32x4 x4 = *(const f32x4*)&x[(((size_t)(b0 + b)) * T + tt) * D + db];
        acc2[b][0] += x4.x * w0.lo; acc2[b][1] += x4.x * w0.hi;
        acc2[b][0] += x4.y * w1.lo; acc2[b][1] += x4.y * w1.hi;
        acc2[b][0] += x4.z * w2.lo; acc2[b][1] += x4.z * w2.hi;
        acc2[b][0] += x4.w * w3.lo; acc2[b][1] += x4.w * w3.hi;
      }
    }
#pragma unroll
    for (int j = 0; j < NPF; ++j) {
      const float* Uj = Up + (size_t)(64 * j) * G4;
#pragma unroll
      for (int r = 0; r < 4; ++r)
        upf[j][r] = *(const f32x4*)(Uj + (size_t)r * G4);
    }
  };

  prefetch(0);

  for (int t = 0; t < T; ++t) {
    // ---- wait for h(t-1): wave0 lanes watch the 32 flags ----
    if (t > 0) {
      if (tid < 64) {
        const unsigned target = (unsigned)t;
        const unsigned* fl = myflags + (tid & 31);
        while (__hip_atomic_load(fl, __ATOMIC_RELAXED, __HIP_MEMORY_SCOPE_AGENT) < target)
          __builtin_amdgcn_s_sleep(1);
        asm volatile("" ::: "memory");
      }
      __syncthreads();
      const unsigned long long* src = (const unsigned long long*)
          (hbuf + ((size_t)(((t - 1) & 1) * B + b0)) * H);
#pragma unroll
      for (int i = 0; i < (NB * H / 2) / THREADS; ++i)   // 4 x 8B per thread
        ((unsigned long long*)&h_lds[0][0])[tid + i * THREADS] =
            __hip_atomic_load(src + tid + i * THREADS,
                              __ATOMIC_RELAXED, __HIP_MEMORY_SCOPE_AGENT);
    } else {
      const f32x4* hsrc = (const f32x4*)(h0 + (size_t)b0 * H);
#pragma unroll
      for (int i = 0; i < (NB * H / 4) / THREADS; ++i)
        ((f32x4*)&h_lds[0][0])[tid + i * THREADS] = hsrc[tid + i * THREADS];
    }
    __syncthreads();

    // ---- issue j=NPF..7 U loads (L2 hits; complete under the FMA stream) ----
    f32x4 u6[4], u7[4];
#pragma unroll
    for (int r = 0; r < 4; ++r) {
      u6[r] = *(const f32x4*)(Up + (size_t)(64 * 6 + r) * G4);
      u7[r] = *(const f32x4*)(Up + (size_t)(64 * 7 + r) * G4);
    }

    // ---- h @ U (packed f32: v_pk_fma_f32) ----
#pragma unroll
    for (int j = 0; j < 8; ++j) {
      f32x4 u0, u1, u2, u3;
      if (j < NPF) { u0 = upf[j][0]; u1 = upf[j][1]; u2 = upf[j][2]; u3 = upf[j][3]; }
      else if (j == 6) { u0 = u6[0]; u1 = u6[1]; u2 = u6[2]; u3 = u6[3]; }
      else { u0 = u7[0]; u1 = u7[1]; u2 = u7[2]; u3 = u7[3]; }
      const int kb = 64 * j + 4 * ks;
#pragma unroll
      for (int b = 0; b < NB; ++b) {
        f32x4 h4 = *(const f32x4*)&h_lds[b][kb];
        acc2[b][0] += h4.x * u0.lo; acc2[b][1] += h4.x * u0.hi;
        acc2[b][0] += h4.y * u1.lo; acc2[b][1] += h4.y * u1.hi;
        acc2[b][0] += h4.z * u2.lo; acc2[b][1] += h4.z * u2.hi;
        acc2[b][0] += h4.w * u3.lo; acc2[b][1] += h4.w * u3.hi;
      }
    }

    // ---- store partials, reduce across 16 k-splits, activation ----
#pragma unroll
    for (int b = 0; b < NB; ++b)
      *(f32x4*)&zpart[ks * ZSTRIDE + b * NCC + cc0] =
          (f32x4){acc2[b][0].x, acc2[b][0].y, acc2[b][1].x, acc2[b][1].y};
    __syncthreads();

    {
      float s = bias_r;
#pragma unroll
      for (int k2 = 0; k2 < KS; ++k2) s += zpart[k2 * ZSTRIDE + rb * NCC + rcc];
      zfull[rb][rcc] = (rgate == 2) ? tanhf_fast(s) : sigf(s);
    }
    __syncthreads();

    // ---- c/h update + SIGNAL (wave0 only; no syncthreads on this path) ----
    if (tid < NB * NC) {
      int b = tid >> 4, hc = tid & 15;
      float ii = zfull[b][hc];
      float ff = zfull[b][NC + hc];
      float gg = zfull[b][2 * NC + hc];
      float oo = zfull[b][3 * NC + hc];
      float c  = ff * c_lds[b][hc] + ii * gg;
      c_lds[b][hc] = c;
      float hn = oo * tanhf_fast(c);
      __hip_atomic_store(hbuf + ((size_t)((t & 1) * B + b0 + b)) * H + hc0 + hc,
                         hn, __ATOMIC_RELAXED, __HIP_MEMORY_SCOPE_AGENT);
      // drain THIS wave's h stores to the coherence point, then raise flag
      asm volatile("s_waitcnt vmcnt(0)" ::: "memory");
      if (tid == 0)
        __hip_atomic_store(myflags + cg, (unsigned)(t + 1),
                           __ATOMIC_RELAXED, __HIP_MEMORY_SCOPE_AGENT);
      // hs stream store AFTER the flag (off the critical path)
      __builtin_nontemporal_store(hn, &hs[(((size_t)(b0 + b)) * T + t) * H + hc0 + hc]);
    }

    // ---- prefetch next step (registers only; overlaps the spin) ----
    prefetch(t + 1 < T ? t + 1 : T - 1);
  }
}

// ---- output projection: out[M,256] = hs[M,512] @ Wo[512,256] + bo ----
__global__ __launch_bounds__(256) void out_gemm(
    const float* __restrict__ A, const float* __restrict__ Wo,
    const float* __restrict__ bo, float* __restrict__ out)
{
  __shared__ float As[64][33];
  __shared__ float Bs[32][64];
  const int m0 = blockIdx.x * 64;
  const int n0 = blockIdx.y * 64;
  const int tid = threadIdx.x;
  const int tx = tid & 15, ty = tid >> 4;

  float acc[4][4];
#pragma unroll
  for (int i = 0; i < 4; ++i)
#pragma unroll
    for (int j = 0; j < 4; ++j) acc[i][j] = 0.f;

  for (int k0 = 0; k0 < 512; k0 += 32) {
#pragma unroll
    for (int it = 0; it < 2; ++it) {
      int r  = (tid >> 3) + it * 32;
      int kq = (tid & 7) * 4;
      float4 vv = *(const float4*)&A[(size_t)(m0 + r) * 512 + k0 + kq];
      As[r][kq + 0] = vv.x; As[r][kq + 1] = vv.y; As[r][kq + 2] = vv.z; As[r][kq + 3] = vv.w;
    }
#pragma unroll
    for (int it = 0; it < 2; ++it) {
      int kk = (tid >> 4) + it * 16;
      int nq = (tid & 15) * 4;
      *(float4*)&Bs[kk][nq] = *(const float4*)&Wo[(size_t)(k0 + kk) * 256 + n0 + nq];
    }
    __syncthreads();
#pragma unroll
    for (int kk = 0; kk < 32; ++kk) {
      float a[4], b[4];
#pragma unroll
      for (int i = 0; i < 4; ++i) a[i] = As[ty * 4 + i][kk];
#pragma unroll
      for (int j = 0; j < 4; ++j) b[j] = Bs[kk][tx * 4 + j];
#pragma unroll
      for (int i = 0; i < 4; ++i)
#pragma unroll
        for (int j = 0; j < 4; ++j) acc[i][j] += a[i] * b[j];
    }
    __syncthreads();
  }
#pragma unroll
  for (int i = 0; i < 4; ++i) {
    int m = m0 + ty * 4 + i;
#pragma unroll
    for (int j = 0; j < 4; ++j) {
      int n = n0 + tx * 4 + j;
      out[(size_t)m * 256 + n] = acc[i][j] + bo[n];
    }
  }
}

extern "C" void kernel_launch(void* const* d_in, const int* in_sizes, int n_in,
                              void* d_out, int out_size, void* d_ws, size_t ws_size,
                              hipStream_t stream) {
  const float* x  = (const float*)d_in[0];
  const float* h0 = (const float*)d_in[1];
  const float* c0 = (const float*)d_in[2];
  const float* W  = (const float*)d_in[3];
  const float* U  = (const float*)d_in[4];
  const float* bv = (const float*)d_in[5];
  const float* Wo = (const float*)d_in[6];
  const float* bo = (const float*)d_in[7];
  float* out = (float*)d_out;

  float*    hs   = (float*)d_ws;                       // 64 MB
  float*    hbuf = hs + (size_t)B * T * H;             // 256 KB
  unsigned* ctr  = (unsigned*)(hbuf + 2 * (size_t)B * H);

  hipLaunchKernelGGL(zero_ctr, dim3(1), dim3(256), 0, stream, ctr);
  hipLaunchKernelGGL(lstm_seq, dim3(GB * GC), dim3(THREADS), 0, stream,
                     x, h0, c0, W, U, bv, hs, hbuf, ctr);
  hipLaunchKernelGGL(out_gemm, dim3((B * T) / 64, 256 / 64), dim3(256), 0, stream,
                     hs, Wo, bo, out);
}

// Round 8
// 2537.134 us; speedup vs baseline: 3.9154x; 1.2293x over previous
//
#include <hip/hip_runtime.h>
#include <cstdint>
#include <cstddef>

// LSTM: B=64, T=512, D=128, H=512, O=256.
// R8: weights IN REGISTERS. A prep kernel repacks U (f16 pairs) and W (f32)
// into per-thread-contiguous tiles; each thread loads its step-invariant
// slice ONCE before the T-loop (U: 64 VGPR, W: 32 VGPR) -> zero weight
// traffic in steady state (R7 showed 342MB of L2-miss refetch from the 8KB
// power-of-2 row stride aliasing L2 sets). h@U uses v_dot2 f16 (fdot2,
// f32 accumulate); h / hs exchanged as packed f16 pairs.
// Persistent 512 wgs (2/CU), 16 batch-groups x 32 col-groups, flag-array
// barrier, decorrelated co-resident groups, fast signal path (all from R7).
// Workspace: hs f16 32MB + hbuf f16 128KB + flags 2KB + Upk 2MB + Wpk 1MB.

namespace {
constexpr int B  = 64;
constexpr int T  = 512;
constexpr int D  = 128;
constexpr int H  = 512;
constexpr int G4 = 4 * H;          // 2048
constexpr int GB = 16;             // batch groups
constexpr int GC = 32;             // col groups
constexpr int NB = B / GB;         // 4 batches per wg
constexpr int NC = H / GC;         // 16 h-cols per wg
constexpr int NCC = 4 * NC;        // 64 gate cols per wg
constexpr int THREADS = 256;
constexpr int KS = 16;             // k-splits: each thread owns 32 of K=512, 8 of D=128
constexpr int ZSTRIDE = NB * NCC + 4;  // 260
constexpr int H2 = H / 2;          // 256 f16-pairs per batch row
}

typedef float    f32x4 __attribute__((ext_vector_type(4)));
typedef _Float16 hf2   __attribute__((ext_vector_type(2)));

__device__ __forceinline__ float sigf(float z) {
  return __fdividef(1.0f, 1.0f + __expf(-z));
}
__device__ __forceinline__ float tanhf_fast(float z) {
  float e = __expf(2.0f * z);
  return 1.0f - __fdividef(2.0f, e + 1.0f);
}

__global__ void zero_ctr(unsigned* __restrict__ c) {
  c[threadIdx.x] = 0u;
  c[threadIdx.x + 256] = 0u;   // 16*32 flags
}

// Repack weights into per-thread-contiguous tiles.
// Upk: [cg][ks][c(64)][kp(16)] hf2   (k = 32*ks + 2*kp, gate col = gcol(c))
// Wpk: [cg][ks][c(64)][r(8)]  f32   (k = 8*ks + r)
__global__ __launch_bounds__(64) void pack_weights(
    const float* __restrict__ U, const float* __restrict__ W,
    hf2* __restrict__ Upk, float* __restrict__ Wpk) {
  const int cg = blockIdx.x, ks = blockIdx.y, c = threadIdx.x;
  const int gcol = (c >> 4) * H + cg * NC + (c & 15);
  hf2* up = Upk + (((size_t)cg * 16 + ks) * 64 + c) * 16;
#pragma unroll
  for (int kp = 0; kp < 16; ++kp) {
    int k = ks * 32 + kp * 2;
    up[kp] = (hf2){(_Float16)U[(size_t)k * G4 + gcol],
                   (_Float16)U[(size_t)(k + 1) * G4 + gcol]};
  }
  float* wp = Wpk + (((size_t)cg * 16 + ks) * 64 + c) * 8;
#pragma unroll
  for (int r = 0; r < 8; ++r)
    wp[r] = W[(size_t)(ks * 8 + r) * G4 + gcol];
}

__global__ __launch_bounds__(THREADS, 2) void lstm_seq(
    const float* __restrict__ x, const float* __restrict__ h0,
    const float* __restrict__ c0, const hf2* __restrict__ Upk,
    const float* __restrict__ Wpk, const float* __restrict__ bias,
    unsigned* __restrict__ hs,    // ws [B][T][H2] u32 (f16 pairs)
    unsigned* __restrict__ hbuf,  // ws [2][B][H2] u32 (coherent h exchange)
    unsigned* __restrict__ flags) // ws [16 groups][32 cg]
{
  const int tid = threadIdx.x;
  // XCD-locality remap + co-residency decorrelation (R7)
  const int xcd = blockIdx.x & 7;
  const int v   = (blockIdx.x >> 3) & 31;
  const int p   = blockIdx.x >> 8;
  const int g   = (v & 7) + 8 * p;
  const int cg  = xcd * 4 + (v >> 3);
  const int b0  = g * NB;
  const int hc0 = cg * NC;

  __shared__ unsigned hl[NB * 256];       // 4 KB: f16-pair h (and x staging unused)
  __shared__ float zpart[KS * ZSTRIDE];   // 16.6 KB
  __shared__ float zfull[NB][NCC];        // 1 KB
  __shared__ float c_lds[NB][NC];         // 256 B

  if (tid < NB * NC) {
    int b = tid >> 4, hc = tid & 15;
    c_lds[b][hc] = c0[(size_t)(b0 + b) * H + hc0 + hc];
  }

  const int cq  = tid & 15;          // col quad: cols cc0..cc0+3
  const int ks  = tid >> 4;          // k-split: k in [32ks,32ks+32), d in [8ks,8ks+8)
  const int cc0 = cq * 4;

  const int rb  = tid >> 6;          // reduce phase: this thread owns (rb, rcc)
  const int rcc = tid & 63;
  const int rgate = rcc >> 4;
  const float bias_r = bias[rgate * H + hc0 + (rcc & 15)];

  unsigned* myflags = flags + g * 32;

  // ---- load step-invariant weight slices into registers (once) ----
  hf2  u[4][16];   // 64 VGPR: U slice, u[cx][kp]
  float w[4][8];   //  32 VGPR: W slice, w[cx][r]
  {
    const hf2* up = Upk + (((size_t)cg * 16 + ks) * 64 + cc0) * 16;
    const float* wp = Wpk + (((size_t)cg * 16 + ks) * 64 + cc0) * 8;
#pragma unroll
    for (int cx = 0; cx < 4; ++cx) {
#pragma unroll
      for (int kp = 0; kp < 16; ++kp) u[cx][kp] = up[cx * 16 + kp];
#pragma unroll
      for (int r = 0; r < 8; ++r) w[cx][r] = wp[cx * 8 + r];
    }
  }

  float acc[NB][4];

  // x @ W partials for step tt (h-independent; overlaps the spin)
  auto prefetch = [&](int tt) {
#pragma unroll
    for (int b = 0; b < NB; ++b) {
      acc[b][0] = 0.f; acc[b][1] = 0.f; acc[b][2] = 0.f; acc[b][3] = 0.f;
      f32x4 x0 = *(const f32x4*)&x[(((size_t)(b0 + b)) * T + tt) * D + 8 * ks];
      f32x4 x1 = *(const f32x4*)&x[(((size_t)(b0 + b)) * T + tt) * D + 8 * ks + 4];
#pragma unroll
      for (int cx = 0; cx < 4; ++cx) {
        acc[b][cx] += x0.x * w[cx][0] + x0.y * w[cx][1] + x0.z * w[cx][2] + x0.w * w[cx][3];
        acc[b][cx] += x1.x * w[cx][4] + x1.y * w[cx][5] + x1.z * w[cx][6] + x1.w * w[cx][7];
      }
    }
  };

  prefetch(0);

  for (int t = 0; t < T; ++t) {
    // ---- wait for h(t-1) flags ----
    if (t > 0) {
      if (tid < 64) {
        const unsigned target = (unsigned)t;
        const unsigned* fl = myflags + (tid & 31);
        while (__hip_atomic_load(fl, __ATOMIC_RELAXED, __HIP_MEMORY_SCOPE_AGENT) < target)
          __builtin_amdgcn_s_sleep(1);
        asm volatile("" ::: "memory");
      }
      __syncthreads();
      // stage h(t-1): 4 u32 per thread (thread tid = pair-word tid of each b)
      const unsigned* src = hbuf + (size_t)(((t - 1) & 1) * B + b0) * H2;
#pragma unroll
      for (int b = 0; b < NB; ++b)
        hl[b * 256 + tid] = __hip_atomic_load(src + b * H2 + tid,
                                              __ATOMIC_RELAXED, __HIP_MEMORY_SCOPE_AGENT);
    } else {
#pragma unroll
      for (int b = 0; b < NB; ++b) {
        hf2 pk = (hf2){(_Float16)h0[(size_t)(b0 + b) * H + 2 * tid],
                       (_Float16)h0[(size_t)(b0 + b) * H + 2 * tid + 1]};
        hl[b * 256 + tid] = __builtin_bit_cast(unsigned, pk);
      }
    }
    __syncthreads();

    // ---- h @ U: fdot2 from registers (U slice resident in VGPRs) ----
#pragma unroll
    for (int b = 0; b < NB; ++b) {
      f32x4 hp0 = *(const f32x4*)&hl[b * 256 + ks * 16 + 0];
      f32x4 hp1 = *(const f32x4*)&hl[b * 256 + ks * 16 + 4];
      f32x4 hp2 = *(const f32x4*)&hl[b * 256 + ks * 16 + 8];
      f32x4 hp3 = *(const f32x4*)&hl[b * 256 + ks * 16 + 12];
      hf2 hp[16];
#pragma unroll
      for (int q = 0; q < 4; ++q) {
        hp[q * 4 + 0] = __builtin_bit_cast(hf2, (q == 0 ? hp0.x : q == 1 ? hp1.x : q == 2 ? hp2.x : hp3.x));
        hp[q * 4 + 1] = __builtin_bit_cast(hf2, (q == 0 ? hp0.y : q == 1 ? hp1.y : q == 2 ? hp2.y : hp3.y));
        hp[q * 4 + 2] = __builtin_bit_cast(hf2, (q == 0 ? hp0.z : q == 1 ? hp1.z : q == 2 ? hp2.z : hp3.z));
        hp[q * 4 + 3] = __builtin_bit_cast(hf2, (q == 0 ? hp0.w : q == 1 ? hp1.w : q == 2 ? hp2.w : hp3.w));
      }
#pragma unroll
      for (int cx = 0; cx < 4; ++cx)
#pragma unroll
        for (int kp = 0; kp < 16; ++kp)
          acc[b][cx] = __builtin_amdgcn_fdot2(hp[kp], u[cx][kp], acc[b][cx], false);
    }

    // ---- store partials, reduce across 16 k-splits, activation ----
#pragma unroll
    for (int b = 0; b < NB; ++b)
      *(f32x4*)&zpart[ks * ZSTRIDE + b * NCC + cc0] =
          (f32x4){acc[b][0], acc[b][1], acc[b][2], acc[b][3]};
    __syncthreads();

    {
      float s = bias_r;
#pragma unroll
      for (int k2 = 0; k2 < KS; ++k2) s += zpart[k2 * ZSTRIDE + rb * NCC + rcc];
      zfull[rb][rcc] = (rgate == 2) ? tanhf_fast(s) : sigf(s);
    }
    __syncthreads();

    // ---- c/h update + fast signal (wave0 only) ----
    if (tid < NB * NC) {
      int b = tid >> 4, hc = tid & 15;
      float ii = zfull[b][hc];
      float ff = zfull[b][NC + hc];
      float gg = zfull[b][2 * NC + hc];
      float oo = zfull[b][3 * NC + hc];
      float c  = ff * c_lds[b][hc] + ii * gg;
      c_lds[b][hc] = c;
      float hn = oo * tanhf_fast(c);
      // pack f16 pair with lane hc^1 (same b)
      float hnb = __shfl_xor(hn, 1);
      unsigned pk = __builtin_bit_cast(unsigned, (hf2){(_Float16)hn, (_Float16)hnb});
      unsigned widx = (unsigned)((hc0 + hc) >> 1);
      if ((hc & 1) == 0) {
        __hip_atomic_store(hbuf + (size_t)((t & 1) * B + b0 + b) * H2 + widx, pk,
                           __ATOMIC_RELAXED, __HIP_MEMORY_SCOPE_AGENT);
      }
      asm volatile("s_waitcnt vmcnt(0)" ::: "memory");
      if (tid == 0)
        __hip_atomic_store(myflags + cg, (unsigned)(t + 1),
                           __ATOMIC_RELAXED, __HIP_MEMORY_SCOPE_AGENT);
      // hs stream store after the flag (off the critical path)
      if ((hc & 1) == 0)
        __builtin_nontemporal_store(pk, hs + ((size_t)(b0 + b) * T + t) * H2 + widx);
    }

    // ---- prefetch next step's x@W (overlaps the spin) ----
    prefetch(t + 1 < T ? t + 1 : T - 1);
  }
}

// ---- out[M,256] = hs_f16[M,512] @ Wo[512,256] + bo ----
__global__ __launch_bounds__(256) void out_gemm(
    const unsigned* __restrict__ A,   // [M][H2] f16-pairs
    const float* __restrict__ Wo,
    const float* __restrict__ bo, float* __restrict__ out)
{
  __shared__ float As[64][33];
  __shared__ float Bs[32][64];
  const int m0 = blockIdx.x * 64;
  const int n0 = blockIdx.y * 64;
  const int tid = threadIdx.x;
  const int tx = tid & 15, ty = tid >> 4;

  float acc[4][4];
#pragma unroll
  for (int i = 0; i < 4; ++i)
#pragma unroll
    for (int j = 0; j < 4; ++j) acc[i][j] = 0.f;

  for (int k0 = 0; k0 < 512; k0 += 32) {
    {   // A tile: 64 rows x 32 k  (16 u32 per row); thread loads 4 u32
      int r = tid >> 2, q = tid & 3;
      f32x4 vv = *(const f32x4*)&A[(size_t)(m0 + r) * H2 + (k0 >> 1) + q * 4];
#pragma unroll
      for (int e = 0; e < 4; ++e) {
        hf2 hp = __builtin_bit_cast(hf2, (e == 0 ? vv.x : e == 1 ? vv.y : e == 2 ? vv.z : vv.w));
        As[r][q * 8 + 2 * e]     = (float)hp.x;
        As[r][q * 8 + 2 * e + 1] = (float)hp.y;
      }
    }
#pragma unroll
    for (int it = 0; it < 2; ++it) {
      int kk = (tid >> 4) + it * 16;
      int nq = (tid & 15) * 4;
      *(float4*)&Bs[kk][nq] = *(const float4*)&Wo[(size_t)(k0 + kk) * 256 + n0 + nq];
    }
    __syncthreads();
#pragma unroll
    for (int kk = 0; kk < 32; ++kk) {
      float a[4], b[4];
#pragma unroll
      for (int i = 0; i < 4; ++i) a[i] = As[ty * 4 + i][kk];
#pragma unroll
      for (int j = 0; j < 4; ++j) b[j] = Bs[kk][tx * 4 + j];
#pragma unroll
      for (int i = 0; i < 4; ++i)
#pragma unroll
        for (int j = 0; j < 4; ++j) acc[i][j] += a[i] * b[j];
    }
    __syncthreads();
  }
#pragma unroll
  for (int i = 0; i < 4; ++i) {
    int m = m0 + ty * 4 + i;
#pragma unroll
    for (int j = 0; j < 4; ++j) {
      int n = n0 + tx * 4 + j;
      out[(size_t)m * 256 + n] = acc[i][j] + bo[n];
    }
  }
}

extern "C" void kernel_launch(void* const* d_in, const int* in_sizes, int n_in,
                              void* d_out, int out_size, void* d_ws, size_t ws_size,
                              hipStream_t stream) {
  const float* x  = (const float*)d_in[0];
  const float* h0 = (const float*)d_in[1];
  const float* c0 = (const float*)d_in[2];
  const float* W  = (const float*)d_in[3];
  const float* U  = (const float*)d_in[4];
  const float* bv = (const float*)d_in[5];
  const float* Wo = (const float*)d_in[6];
  const float* bo = (const float*)d_in[7];
  float* out = (float*)d_out;

  unsigned* hs    = (unsigned*)d_ws;                         // 32 MB (f16 pairs)
  unsigned* hbuf  = hs + (size_t)B * T * H2;                 // 128 KB
  unsigned* flags = hbuf + 2 * (size_t)B * H2;               // 2 KB
  hf2*      Upk   = (hf2*)(flags + 512);                     // 2 MB
  float*    Wpk   = (float*)(Upk + (size_t)32 * 16 * 64 * 16); // 1 MB

  hipLaunchKernelGGL(zero_ctr, dim3(1), dim3(256), 0, stream, flags);
  hipLaunchKernelGGL(pack_weights, dim3(32, 16), dim3(64), 0, stream, U, W, Upk, Wpk);
  hipLaunchKernelGGL(lstm_seq, dim3(GB * GC), dim3(THREADS), 0, stream,
                     x, h0, c0, Upk, Wpk, bv, hs, hbuf, flags);
  hipLaunchKernelGGL(out_gemm, dim3((B * T) / 64, 256 / 64), dim3(256), 0, stream,
                     hs, Wo, bo, out);
}

// Round 9
// 2144.973 us; speedup vs baseline: 4.6312x; 1.1828x over previous
//
#include <hip/hip_runtime.h>
#include <cstdint>
#include <cstddef>

// LSTM: B=64, T=512, D=128, H=512, O=256.
// R9: (1) TAGGED-DATA h exchange: producer stores {tag=t+1 | 2xf16} as ONE
// relaxed 8B agent atomic; consumers poll data words directly -> 1 fabric
// RTT instead of 3 (h-store/flag-store/flag-poll). Parity double-buffer +
// exact-tag poll is race-free and 0xAA-poison-proof. No flags, no vmcnt.
// (2) Batch-groups clustered per XCD (g=(blk&7)*2+(blk>>8)): weights now
// live in registers (R8), so the old reason to spread col-groups is gone;
// x is read by ONE XCD -> x HBM traffic 128->16 MB. Co-resident CU pairs
// stay in different groups (stall overlap).
// Carried: weights packed per-thread (U f16 in 64 VGPR, W f32 in 32 VGPR),
// fdot2 math, x@W prefetch overlapping the spin, fast wave0 epilogue.
// Workspace: hs 32MB + hx 256KB + Upk 2MB + Wpk 1MB.

namespace {
constexpr int B  = 64;
constexpr int T  = 512;
constexpr int D  = 128;
constexpr int H  = 512;
constexpr int G4 = 4 * H;          // 2048
constexpr int GB = 16;             // batch groups
constexpr int GC = 32;             // col groups
constexpr int NB = B / GB;         // 4 batches per wg
constexpr int NC = H / GC;         // 16 h-cols per wg
constexpr int NCC = 4 * NC;        // 64 gate cols per wg
constexpr int THREADS = 256;
constexpr int KS = 16;             // k-splits: thread owns 32 of K=512, 8 of D=128
constexpr int ZSTRIDE = NB * NCC + 4;  // 260
constexpr int H2 = H / 2;          // 256 f16-pair words per batch row
}

typedef float    f32x4 __attribute__((ext_vector_type(4)));
typedef _Float16 hf2   __attribute__((ext_vector_type(2)));

__device__ __forceinline__ float sigf(float z) {
  return __fdividef(1.0f, 1.0f + __expf(-z));
}
__device__ __forceinline__ float tanhf_fast(float z) {
  float e = __expf(2.0f * z);
  return 1.0f - __fdividef(2.0f, e + 1.0f);
}

// Repack weights into per-thread-contiguous tiles.
// Upk: [cg][ks][c(64)][kp(16)] hf2   (k = 32*ks + 2*kp, gate col = gcol(c))
// Wpk: [cg][ks][c(64)][r(8)]  f32   (k = 8*ks + r)
__global__ __launch_bounds__(64) void pack_weights(
    const float* __restrict__ U, const float* __restrict__ W,
    hf2* __restrict__ Upk, float* __restrict__ Wpk) {
  const int cg = blockIdx.x, ks = blockIdx.y, c = threadIdx.x;
  const int gcol = (c >> 4) * H + cg * NC + (c & 15);
  hf2* up = Upk + (((size_t)cg * 16 + ks) * 64 + c) * 16;
#pragma unroll
  for (int kp = 0; kp < 16; ++kp) {
    int k = ks * 32 + kp * 2;
    up[kp] = (hf2){(_Float16)U[(size_t)k * G4 + gcol],
                   (_Float16)U[(size_t)(k + 1) * G4 + gcol]};
  }
  float* wp = Wpk + (((size_t)cg * 16 + ks) * 64 + c) * 8;
#pragma unroll
  for (int r = 0; r < 8; ++r)
    wp[r] = W[(size_t)(ks * 8 + r) * G4 + gcol];
}

__global__ __launch_bounds__(THREADS, 2) void lstm_seq(
    const float* __restrict__ x, const float* __restrict__ h0,
    const float* __restrict__ c0, const hf2* __restrict__ Upk,
    const float* __restrict__ Wpk, const float* __restrict__ bias,
    unsigned* __restrict__ hs,              // ws [B][T][H2] u32 (f16 pairs)
    unsigned long long* __restrict__ hx)    // ws [2][B][H2] tagged u64
{
  const int tid = threadIdx.x;
  // --- XCD clustering + co-residency decorrelation ---
  // xcd = blk&7 (round-robin heuristic). Each XCD hosts batch groups
  // {2*xcd, 2*xcd+1}; co-resident pair (blk, blk+256) -> different groups.
  const int xcd = blockIdx.x & 7;
  const int g   = xcd * 2 + (blockIdx.x >> 8);
  const int cg  = (blockIdx.x >> 3) & 31;
  const int b0  = g * NB;
  const int hc0 = cg * NC;

  __shared__ unsigned hl[NB * 256];       // 4 KB f16-pair h
  __shared__ float zpart[KS * ZSTRIDE];   // 16.6 KB
  __shared__ float zfull[NB][NCC];        // 1 KB
  __shared__ float c_lds[NB][NC];         // 256 B

  if (tid < NB * NC) {
    int b = tid >> 4, hc = tid & 15;
    c_lds[b][hc] = c0[(size_t)(b0 + b) * H + hc0 + hc];
  }

  const int cq  = tid & 15;          // col quad: cols cc0..cc0+3
  const int ks  = tid >> 4;          // k-split
  const int cc0 = cq * 4;

  const int rb  = tid >> 6;          // reduce phase: (rb, rcc)
  const int rcc = tid & 63;
  const int rgate = rcc >> 4;
  const float bias_r = bias[rgate * H + hc0 + (rcc & 15)];

  // ---- step-invariant weight slices -> registers (once) ----
  hf2  u[4][16];   // 64 VGPR
  float w[4][8];   // 32 VGPR
  {
    const hf2* up = Upk + (((size_t)cg * 16 + ks) * 64 + cc0) * 16;
    const float* wp = Wpk + (((size_t)cg * 16 + ks) * 64 + cc0) * 8;
#pragma unroll
    for (int cx = 0; cx < 4; ++cx) {
#pragma unroll
      for (int kp = 0; kp < 16; ++kp) u[cx][kp] = up[cx * 16 + kp];
#pragma unroll
      for (int r = 0; r < 8; ++r) w[cx][r] = wp[cx * 8 + r];
    }
  }

  float acc[NB][4];
  auto prefetch = [&](int tt) {   // x@W partials (h-independent)
#pragma unroll
    for (int b = 0; b < NB; ++b) {
      acc[b][0] = 0.f; acc[b][1] = 0.f; acc[b][2] = 0.f; acc[b][3] = 0.f;
      f32x4 x0 = *(const f32x4*)&x[(((size_t)(b0 + b)) * T + tt) * D + 8 * ks];
      f32x4 x1 = *(const f32x4*)&x[(((size_t)(b0 + b)) * T + tt) * D + 8 * ks + 4];
#pragma unroll
      for (int cx = 0; cx < 4; ++cx) {
        acc[b][cx] += x0.x * w[cx][0] + x0.y * w[cx][1] + x0.z * w[cx][2] + x0.w * w[cx][3];
        acc[b][cx] += x1.x * w[cx][4] + x1.y * w[cx][5] + x1.z * w[cx][6] + x1.w * w[cx][7];
      }
    }
  };

  prefetch(0);

  for (int t = 0; t < T; ++t) {
    // ---- stage h(t-1): poll tagged words (parity buffer (t-1)&1) ----
    if (t > 0) {
      const unsigned long long* src = hx + (size_t)(((t - 1) & 1) * B + b0) * H2;
      const unsigned target = (unsigned)t;
#pragma unroll
      for (int i = 0; i < NB; ++i) {
        unsigned long long v;
        do {
          v = __hip_atomic_load(src + i * H2 + tid,
                                __ATOMIC_RELAXED, __HIP_MEMORY_SCOPE_AGENT);
          if ((unsigned)(v >> 32) == target) break;
          __builtin_amdgcn_s_sleep(1);
        } while (true);
        hl[i * 256 + tid] = (unsigned)v;
      }
    } else {
#pragma unroll
      for (int i = 0; i < NB; ++i) {
        hf2 pk = (hf2){(_Float16)h0[(size_t)(b0 + i) * H + 2 * tid],
                       (_Float16)h0[(size_t)(b0 + i) * H + 2 * tid + 1]};
        hl[i * 256 + tid] = __builtin_bit_cast(unsigned, pk);
      }
    }
    __syncthreads();

    // ---- h @ U: fdot2 from registers ----
#pragma unroll
    for (int b = 0; b < NB; ++b) {
      f32x4 hp0 = *(const f32x4*)&hl[b * 256 + ks * 16 + 0];
      f32x4 hp1 = *(const f32x4*)&hl[b * 256 + ks * 16 + 4];
      f32x4 hp2 = *(const f32x4*)&hl[b * 256 + ks * 16 + 8];
      f32x4 hp3 = *(const f32x4*)&hl[b * 256 + ks * 16 + 12];
      hf2 hp[16];
#pragma unroll
      for (int q = 0; q < 4; ++q) {
        hp[q * 4 + 0] = __builtin_bit_cast(hf2, (q == 0 ? hp0.x : q == 1 ? hp1.x : q == 2 ? hp2.x : hp3.x));
        hp[q * 4 + 1] = __builtin_bit_cast(hf2, (q == 0 ? hp0.y : q == 1 ? hp1.y : q == 2 ? hp2.y : hp3.y));
        hp[q * 4 + 2] = __builtin_bit_cast(hf2, (q == 0 ? hp0.z : q == 1 ? hp1.z : q == 2 ? hp2.z : hp3.z));
        hp[q * 4 + 3] = __builtin_bit_cast(hf2, (q == 0 ? hp0.w : q == 1 ? hp1.w : q == 2 ? hp2.w : hp3.w));
      }
#pragma unroll
      for (int cx = 0; cx < 4; ++cx)
#pragma unroll
        for (int kp = 0; kp < 16; ++kp)
          acc[b][cx] = __builtin_amdgcn_fdot2(hp[kp], u[cx][kp], acc[b][cx], false);
    }

    // ---- reduce across 16 k-splits, activation ----
#pragma unroll
    for (int b = 0; b < NB; ++b)
      *(f32x4*)&zpart[ks * ZSTRIDE + b * NCC + cc0] =
          (f32x4){acc[b][0], acc[b][1], acc[b][2], acc[b][3]};
    __syncthreads();

    {
      float s = bias_r;
#pragma unroll
      for (int k2 = 0; k2 < KS; ++k2) s += zpart[k2 * ZSTRIDE + rb * NCC + rcc];
      zfull[rb][rcc] = (rgate == 2) ? tanhf_fast(s) : sigf(s);
    }
    __syncthreads();

    // ---- c/h update + tagged publish (wave0 only; single 8B atomic) ----
    if (tid < NB * NC) {
      int b = tid >> 4, hc = tid & 15;
      float ii = zfull[b][hc];
      float ff = zfull[b][NC + hc];
      float gg = zfull[b][2 * NC + hc];
      float oo = zfull[b][3 * NC + hc];
      float c  = ff * c_lds[b][hc] + ii * gg;
      c_lds[b][hc] = c;
      float hn = oo * tanhf_fast(c);
      float hnb = __shfl_xor(hn, 1);
      unsigned pk = __builtin_bit_cast(unsigned, (hf2){(_Float16)hn, (_Float16)hnb});
      if ((hc & 1) == 0) {
        unsigned widx = (unsigned)((hc0 + hc) >> 1);
        unsigned long long word = ((unsigned long long)(unsigned)(t + 1) << 32) | pk;
        __hip_atomic_store(hx + (size_t)((t & 1) * B + b0 + b) * H2 + widx, word,
                           __ATOMIC_RELAXED, __HIP_MEMORY_SCOPE_AGENT);
        // hs stream store (off the critical path)
        __builtin_nontemporal_store(pk, hs + ((size_t)(b0 + b) * T + t) * H2 + widx);
      }
    }

    // ---- prefetch next step's x@W (overlaps the spin) ----
    prefetch(t + 1 < T ? t + 1 : T - 1);
  }
}

// ---- out[M,256] = hs_f16[M,512] @ Wo[512,256] + bo ----
__global__ __launch_bounds__(256) void out_gemm(
    const unsigned* __restrict__ A,   // [M][H2] f16-pairs
    const float* __restrict__ Wo,
    const float* __restrict__ bo, float* __restrict__ out)
{
  __shared__ float As[64][33];
  __shared__ float Bs[32][64];
  const int m0 = blockIdx.x * 64;
  const int n0 = blockIdx.y * 64;
  const int tid = threadIdx.x;
  const int tx = tid & 15, ty = tid >> 4;

  float acc[4][4];
#pragma unroll
  for (int i = 0; i < 4; ++i)
#pragma unroll
    for (int j = 0; j < 4; ++j) acc[i][j] = 0.f;

  for (int k0 = 0; k0 < 512; k0 += 32) {
    {   // A tile: 64 rows x 32 k; thread loads 4 u32 (f16 pairs)
      int r = tid >> 2, q = tid & 3;
      f32x4 vv = *(const f32x4*)&A[(size_t)(m0 + r) * H2 + (k0 >> 1) + q * 4];
#pragma unroll
      for (int e = 0; e < 4; ++e) {
        hf2 hp = __builtin_bit_cast(hf2, (e == 0 ? vv.x : e == 1 ? vv.y : e == 2 ? vv.z : vv.w));
        As[r][q * 8 + 2 * e]     = (float)hp.x;
        As[r][q * 8 + 2 * e + 1] = (float)hp.y;
      }
    }
#pragma unroll
    for (int it = 0; it < 2; ++it) {
      int kk = (tid >> 4) + it * 16;
      int nq = (tid & 15) * 4;
      *(float4*)&Bs[kk][nq] = *(const float4*)&Wo[(size_t)(k0 + kk) * 256 + n0 + nq];
    }
    __syncthreads();
#pragma unroll
    for (int kk = 0; kk < 32; ++kk) {
      float a[4], b[4];
#pragma unroll
      for (int i = 0; i < 4; ++i) a[i] = As[ty * 4 + i][kk];
#pragma unroll
      for (int j = 0; j < 4; ++j) b[j] = Bs[kk][tx * 4 + j];
#pragma unroll
      for (int i = 0; i < 4; ++i)
#pragma unroll
        for (int j = 0; j < 4; ++j) acc[i][j] += a[i] * b[j];
    }
    __syncthreads();
  }
#pragma unroll
  for (int i = 0; i < 4; ++i) {
    int m = m0 + ty * 4 + i;
#pragma unroll
    for (int j = 0; j < 4; ++j) {
      int n = n0 + tx * 4 + j;
      out[(size_t)m * 256 + n] = acc[i][j] + bo[n];
    }
  }
}

extern "C" void kernel_launch(void* const* d_in, const int* in_sizes, int n_in,
                              void* d_out, int out_size, void* d_ws, size_t ws_size,
                              hipStream_t stream) {
  const float* x  = (const float*)d_in[0];
  const float* h0 = (const float*)d_in[1];
  const float* c0 = (const float*)d_in[2];
  const float* W  = (const float*)d_in[3];
  const float* U  = (const float*)d_in[4];
  const float* bv = (const float*)d_in[5];
  const float* Wo = (const float*)d_in[6];
  const float* bo = (const float*)d_in[7];
  float* out = (float*)d_out;

  unsigned*           hs  = (unsigned*)d_ws;                    // 32 MB
  unsigned long long* hx  = (unsigned long long*)(hs + (size_t)B * T * H2);  // 256 KB
  hf2*   Upk = (hf2*)(hx + 2 * (size_t)B * H2);                 // 2 MB
  float* Wpk = (float*)(Upk + (size_t)32 * 16 * 64 * 16);       // 1 MB

  hipLaunchKernelGGL(pack_weights, dim3(32, 16), dim3(64), 0, stream, U, W, Upk, Wpk);
  hipLaunchKernelGGL(lstm_seq, dim3(GB * GC), dim3(THREADS), 0, stream,
                     x, h0, c0, Upk, Wpk, bv, hs, hx);
  hipLaunchKernelGGL(out_gemm, dim3((B * T) / 64, 256 / 64), dim3(256), 0, stream,
                     hs, Wo, bo, out);
}

// Round 10
// 2005.988 us; speedup vs baseline: 4.9521x; 1.0693x over previous
//
#include <hip/hip_runtime.h>
#include <cstdint>
#include <cstddef>

// LSTM: B=64, T=512, D=128, H=512, O=256.
// R10: exchange latency attack.
//  (1) PARALLEL poll: one asm block issues 4 sc0 tag-word loads + single
//      vmcnt(0) -> 1 RTT instead of 4 serial (R9's per-word do-while).
//  (2) DUAL-PUBLISH: producer stores tagged word to a PLAIN buffer (local
//      L2 fast path, ~200cy for same-XCD consumers) AND an agent-scope
//      mirror (fabric, placement-safety). Consumers poll fast buffer via
//      sc0 (L1-bypass) loads; every 8th spin fall back to the agent mirror.
//      Tags self-validate -> correct for ANY placement; fast under the
//      round-robin heuristic (whole batch-group on one XCD).
// Carried from R8/R9: weights in registers (U f16 64 VGPR + W f32 32 VGPR,
// per-thread packed), fdot2 math, XCD-clustered batch groups, decorrelated
// co-resident chains, x@W prefetch overlapping the spin, f16 h/hs.
// Workspace: hs 32MB + hx 256KB + hxf 256KB + Upk 2MB + Wpk 1MB.

namespace {
constexpr int B  = 64;
constexpr int T  = 512;
constexpr int D  = 128;
constexpr int H  = 512;
constexpr int G4 = 4 * H;          // 2048
constexpr int GB = 16;             // batch groups
constexpr int GC = 32;             // col groups
constexpr int NB = B / GB;         // 4 batches per wg
constexpr int NC = H / GC;         // 16 h-cols per wg
constexpr int NCC = 4 * NC;        // 64 gate cols per wg
constexpr int THREADS = 256;
constexpr int KS = 16;             // k-splits: thread owns 32 of K=512, 8 of D=128
constexpr int ZSTRIDE = NB * NCC + 4;  // 260
constexpr int H2 = H / 2;          // 256 f16-pair words per batch row
}

typedef float    f32x4 __attribute__((ext_vector_type(4)));
typedef _Float16 hf2   __attribute__((ext_vector_type(2)));

__device__ __forceinline__ float sigf(float z) {
  return __fdividef(1.0f, 1.0f + __expf(-z));
}
__device__ __forceinline__ float tanhf_fast(float z) {
  float e = __expf(2.0f * z);
  return 1.0f - __fdividef(2.0f, e + 1.0f);
}

// 4 independent 8B loads, L1-bypass (sc0), single wait -> ~1 RTT total.
__device__ __forceinline__ void load4_sc0(
    const unsigned long long* p0, const unsigned long long* p1,
    const unsigned long long* p2, const unsigned long long* p3,
    unsigned long long& r0, unsigned long long& r1,
    unsigned long long& r2, unsigned long long& r3) {
  asm volatile(
      "global_load_dwordx2 %0, %4, off sc0\n\t"
      "global_load_dwordx2 %1, %5, off sc0\n\t"
      "global_load_dwordx2 %2, %6, off sc0\n\t"
      "global_load_dwordx2 %3, %7, off sc0\n\t"
      "s_waitcnt vmcnt(0)"
      : "=&v"(r0), "=&v"(r1), "=&v"(r2), "=&v"(r3)
      : "v"(p0), "v"(p1), "v"(p2), "v"(p3)
      : "memory");
}

// Repack weights into per-thread-contiguous tiles.
__global__ __launch_bounds__(64) void pack_weights(
    const float* __restrict__ U, const float* __restrict__ W,
    hf2* __restrict__ Upk, float* __restrict__ Wpk) {
  const int cg = blockIdx.x, ks = blockIdx.y, c = threadIdx.x;
  const int gcol = (c >> 4) * H + cg * NC + (c & 15);
  hf2* up = Upk + (((size_t)cg * 16 + ks) * 64 + c) * 16;
#pragma unroll
  for (int kp = 0; kp < 16; ++kp) {
    int k = ks * 32 + kp * 2;
    up[kp] = (hf2){(_Float16)U[(size_t)k * G4 + gcol],
                   (_Float16)U[(size_t)(k + 1) * G4 + gcol]};
  }
  float* wp = Wpk + (((size_t)cg * 16 + ks) * 64 + c) * 8;
#pragma unroll
  for (int r = 0; r < 8; ++r)
    wp[r] = W[(size_t)(ks * 8 + r) * G4 + gcol];
}

__global__ __launch_bounds__(THREADS, 2) void lstm_seq(
    const float* __restrict__ x, const float* __restrict__ h0,
    const float* __restrict__ c0, const hf2* __restrict__ Upk,
    const float* __restrict__ Wpk, const float* __restrict__ bias,
    unsigned* __restrict__ hs,              // ws [B][T][H2] u32 (f16 pairs)
    unsigned long long* __restrict__ hx,    // ws [2][B][H2] tagged u64 (agent mirror)
    unsigned long long* __restrict__ hxf)   // ws [2][B][H2] tagged u64 (L2 fast path)
{
  const int tid = threadIdx.x;
  // XCD clustering + co-residency decorrelation (R9)
  const int xcd = blockIdx.x & 7;
  const int g   = xcd * 2 + (blockIdx.x >> 8);
  const int cg  = (blockIdx.x >> 3) & 31;
  const int b0  = g * NB;
  const int hc0 = cg * NC;

  __shared__ unsigned hl[NB * 256];       // 4 KB f16-pair h
  __shared__ float zpart[KS * ZSTRIDE];   // 16.6 KB
  __shared__ float zfull[NB][NCC];        // 1 KB
  __shared__ float c_lds[NB][NC];         // 256 B

  if (tid < NB * NC) {
    int b = tid >> 4, hc = tid & 15;
    c_lds[b][hc] = c0[(size_t)(b0 + b) * H + hc0 + hc];
  }

  const int cq  = tid & 15;          // col quad: cols cc0..cc0+3
  const int ks  = tid >> 4;          // k-split
  const int cc0 = cq * 4;

  const int rb  = tid >> 6;          // reduce phase: (rb, rcc)
  const int rcc = tid & 63;
  const int rgate = rcc >> 4;
  const float bias_r = bias[rgate * H + hc0 + (rcc & 15)];

  // ---- step-invariant weight slices -> registers (once) ----
  hf2  u[4][16];   // 64 VGPR
  float w[4][8];   // 32 VGPR
  {
    const hf2* up = Upk + (((size_t)cg * 16 + ks) * 64 + cc0) * 16;
    const float* wp = Wpk + (((size_t)cg * 16 + ks) * 64 + cc0) * 8;
#pragma unroll
    for (int cx = 0; cx < 4; ++cx) {
#pragma unroll
      for (int kp = 0; kp < 16; ++kp) u[cx][kp] = up[cx * 16 + kp];
#pragma unroll
      for (int r = 0; r < 8; ++r) w[cx][r] = wp[cx * 8 + r];
    }
  }

  float acc[NB][4];
  auto prefetch = [&](int tt) {   // x@W partials (h-independent)
#pragma unroll
    for (int b = 0; b < NB; ++b) {
      acc[b][0] = 0.f; acc[b][1] = 0.f; acc[b][2] = 0.f; acc[b][3] = 0.f;
      f32x4 x0 = *(const f32x4*)&x[(((size_t)(b0 + b)) * T + tt) * D + 8 * ks];
      f32x4 x1 = *(const f32x4*)&x[(((size_t)(b0 + b)) * T + tt) * D + 8 * ks + 4];
#pragma unroll
      for (int cx = 0; cx < 4; ++cx) {
        acc[b][cx] += x0.x * w[cx][0] + x0.y * w[cx][1] + x0.z * w[cx][2] + x0.w * w[cx][3];
        acc[b][cx] += x1.x * w[cx][4] + x1.y * w[cx][5] + x1.z * w[cx][6] + x1.w * w[cx][7];
      }
    }
  };

  prefetch(0);

  for (int t = 0; t < T; ++t) {
    // ---- stage h(t-1): parallel tagged poll (fast L2 path + agent fallback) ----
    if (t > 0) {
      const size_t base = (size_t)(((t - 1) & 1) * B + b0) * H2 + tid;
      const unsigned long long* pf = hxf + base;
      const unsigned long long* pm = hx + base;
      const unsigned target = (unsigned)t;
      unsigned long long v0, v1, v2, v3;
      unsigned spin = 0;
      while (true) {
        if ((spin & 7) == 7) {   // placement-safety fallback (fabric mirror)
          v0 = __hip_atomic_load(pm + 0 * H2, __ATOMIC_RELAXED, __HIP_MEMORY_SCOPE_AGENT);
          v1 = __hip_atomic_load(pm + 1 * H2, __ATOMIC_RELAXED, __HIP_MEMORY_SCOPE_AGENT);
          v2 = __hip_atomic_load(pm + 2 * H2, __ATOMIC_RELAXED, __HIP_MEMORY_SCOPE_AGENT);
          v3 = __hip_atomic_load(pm + 3 * H2, __ATOMIC_RELAXED, __HIP_MEMORY_SCOPE_AGENT);
        } else {                 // fast path: sc0 loads served by local L2
          load4_sc0(pf, pf + H2, pf + 2 * H2, pf + 3 * H2, v0, v1, v2, v3);
        }
        if ((unsigned)(v0 >> 32) == target && (unsigned)(v1 >> 32) == target &&
            (unsigned)(v2 >> 32) == target && (unsigned)(v3 >> 32) == target)
          break;
        ++spin;
        __builtin_amdgcn_s_sleep(1);
      }
      hl[0 * 256 + tid] = (unsigned)v0;
      hl[1 * 256 + tid] = (unsigned)v1;
      hl[2 * 256 + tid] = (unsigned)v2;
      hl[3 * 256 + tid] = (unsigned)v3;
    } else {
#pragma unroll
      for (int i = 0; i < NB; ++i) {
        hf2 pk = (hf2){(_Float16)h0[(size_t)(b0 + i) * H + 2 * tid],
                       (_Float16)h0[(size_t)(b0 + i) * H + 2 * tid + 1]};
        hl[i * 256 + tid] = __builtin_bit_cast(unsigned, pk);
      }
    }
    __syncthreads();

    // ---- h @ U: fdot2 from registers ----
#pragma unroll
    for (int b = 0; b < NB; ++b) {
      f32x4 hp0 = *(const f32x4*)&hl[b * 256 + ks * 16 + 0];
      f32x4 hp1 = *(const f32x4*)&hl[b * 256 + ks * 16 + 4];
      f32x4 hp2 = *(const f32x4*)&hl[b * 256 + ks * 16 + 8];
      f32x4 hp3 = *(const f32x4*)&hl[b * 256 + ks * 16 + 12];
      hf2 hp[16];
#pragma unroll
      for (int q = 0; q < 4; ++q) {
        hp[q * 4 + 0] = __builtin_bit_cast(hf2, (q == 0 ? hp0.x : q == 1 ? hp1.x : q == 2 ? hp2.x : hp3.x));
        hp[q * 4 + 1] = __builtin_bit_cast(hf2, (q == 0 ? hp0.y : q == 1 ? hp1.y : q == 2 ? hp2.y : hp3.y));
        hp[q * 4 + 2] = __builtin_bit_cast(hf2, (q == 0 ? hp0.z : q == 1 ? hp1.z : q == 2 ? hp2.z : hp3.z));
        hp[q * 4 + 3] = __builtin_bit_cast(hf2, (q == 0 ? hp0.w : q == 1 ? hp1.w : q == 2 ? hp2.w : hp3.w));
      }
#pragma unroll
      for (int cx = 0; cx < 4; ++cx)
#pragma unroll
        for (int kp = 0; kp < 16; ++kp)
          acc[b][cx] = __builtin_amdgcn_fdot2(hp[kp], u[cx][kp], acc[b][cx], false);
    }

    // ---- reduce across 16 k-splits, activation ----
#pragma unroll
    for (int b = 0; b < NB; ++b)
      *(f32x4*)&zpart[ks * ZSTRIDE + b * NCC + cc0] =
          (f32x4){acc[b][0], acc[b][1], acc[b][2], acc[b][3]};
    __syncthreads();

    {
      float s = bias_r;
#pragma unroll
      for (int k2 = 0; k2 < KS; ++k2) s += zpart[k2 * ZSTRIDE + rb * NCC + rcc];
      zfull[rb][rcc] = (rgate == 2) ? tanhf_fast(s) : sigf(s);
    }
    __syncthreads();

    // ---- c/h update + dual tagged publish (wave0 only) ----
    if (tid < NB * NC) {
      int b = tid >> 4, hc = tid & 15;
      float ii = zfull[b][hc];
      float ff = zfull[b][NC + hc];
      float gg = zfull[b][2 * NC + hc];
      float oo = zfull[b][3 * NC + hc];
      float c  = ff * c_lds[b][hc] + ii * gg;
      c_lds[b][hc] = c;
      float hn = oo * tanhf_fast(c);
      float hnb = __shfl_xor(hn, 1);
      unsigned pk = __builtin_bit_cast(unsigned, (hf2){(_Float16)hn, (_Float16)hnb});
      if ((hc & 1) == 0) {
        size_t idx = (size_t)((t & 1) * B + b0 + b) * H2 + ((hc0 + hc) >> 1);
        unsigned long long word = ((unsigned long long)(unsigned)(t + 1) << 32) | pk;
        hxf[idx] = word;                        // fast path: local L2
        __hip_atomic_store(hx + idx, word,      // safety: fabric mirror
                           __ATOMIC_RELAXED, __HIP_MEMORY_SCOPE_AGENT);
        __builtin_nontemporal_store(pk, hs + ((size_t)(b0 + b) * T + t) * H2 + ((hc0 + hc) >> 1));
      }
    }

    // ---- prefetch next step's x@W (overlaps the spin) ----
    prefetch(t + 1 < T ? t + 1 : T - 1);
  }
}

// ---- out[M,256] = hs_f16[M,512] @ Wo[512,256] + bo ----
__global__ __launch_bounds__(256) void out_gemm(
    const unsigned* __restrict__ A,   // [M][H2] f16-pairs
    const float* __restrict__ Wo,
    const float* __restrict__ bo, float* __restrict__ out)
{
  __shared__ float As[64][33];
  __shared__ float Bs[32][64];
  const int m0 = blockIdx.x * 64;
  const int n0 = blockIdx.y * 64;
  const int tid = threadIdx.x;
  const int tx = tid & 15, ty = tid >> 4;

  float acc[4][4];
#pragma unroll
  for (int i = 0; i < 4; ++i)
#pragma unroll
    for (int j = 0; j < 4; ++j) acc[i][j] = 0.f;

  for (int k0 = 0; k0 < 512; k0 += 32) {
    {   // A tile: 64 rows x 32 k; thread loads 4 u32 (f16 pairs)
      int r = tid >> 2, q = tid & 3;
      f32x4 vv = *(const f32x4*)&A[(size_t)(m0 + r) * H2 + (k0 >> 1) + q * 4];
#pragma unroll
      for (int e = 0; e < 4; ++e) {
        hf2 hp = __builtin_bit_cast(hf2, (e == 0 ? vv.x : e == 1 ? vv.y : e == 2 ? vv.z : vv.w));
        As[r][q * 8 + 2 * e]     = (float)hp.x;
        As[r][q * 8 + 2 * e + 1] = (float)hp.y;
      }
    }
#pragma unroll
    for (int it = 0; it < 2; ++it) {
      int kk = (tid >> 4) + it * 16;
      int nq = (tid & 15) * 4;
      *(float4*)&Bs[kk][nq] = *(const float4*)&Wo[(size_t)(k0 + kk) * 256 + n0 + nq];
    }
    __syncthreads();
#pragma unroll
    for (int kk = 0; kk < 32; ++kk) {
      float a[4], b[4];
#pragma unroll
      for (int i = 0; i < 4; ++i) a[i] = As[ty * 4 + i][kk];
#pragma unroll
      for (int j = 0; j < 4; ++j) b[j] = Bs[kk][tx * 4 + j];
#pragma unroll
      for (int i = 0; i < 4; ++i)
#pragma unroll
        for (int j = 0; j < 4; ++j) acc[i][j] += a[i] * b[j];
    }
    __syncthreads();
  }
#pragma unroll
  for (int i = 0; i < 4; ++i) {
    int m = m0 + ty * 4 + i;
#pragma unroll
    for (int j = 0; j < 4; ++j) {
      int n = n0 + tx * 4 + j;
      out[(size_t)m * 256 + n] = acc[i][j] + bo[n];
    }
  }
}

extern "C" void kernel_launch(void* const* d_in, const int* in_sizes, int n_in,
                              void* d_out, int out_size, void* d_ws, size_t ws_size,
                              hipStream_t stream) {
  const float* x  = (const float*)d_in[0];
  const float* h0 = (const float*)d_in[1];
  const float* c0 = (const float*)d_in[2];
  const float* W  = (const float*)d_in[3];
  const float* U  = (const float*)d_in[4];
  const float* bv = (const float*)d_in[5];
  const float* Wo = (const float*)d_in[6];
  const float* bo = (const float*)d_in[7];
  float* out = (float*)d_out;

  unsigned*           hs  = (unsigned*)d_ws;                              // 32 MB
  unsigned long long* hx  = (unsigned long long*)(hs + (size_t)B * T * H2);   // 256 KB
  unsigned long long* hxf = hx + 2 * (size_t)B * H2;                      // 256 KB
  hf2*   Upk = (hf2*)(hxf + 2 * (size_t)B * H2);                          // 2 MB
  float* Wpk = (float*)(Upk + (size_t)32 * 16 * 64 * 16);                 // 1 MB

  hipLaunchKernelGGL(pack_weights, dim3(32, 16), dim3(64), 0, stream, U, W, Upk, Wpk);
  hipLaunchKernelGGL(lstm_seq, dim3(GB * GC), dim3(THREADS), 0, stream,
                     x, h0, c0, Upk, Wpk, bv, hs, hx, hxf);
  hipLaunchKernelGGL(out_gemm, dim3((B * T) / 64, 256 / 64), dim3(256), 0, stream,
                     hs, Wo, bo, out);
}